// Round 1
// baseline (761.524 us; speedup 1.0000x reference)
//
#include <hip/hip_runtime.h>

typedef unsigned short u16;
typedef __attribute__((ext_vector_type(8))) short bfx8;
typedef __attribute__((ext_vector_type(4))) float fx4;
typedef __attribute__((ext_vector_type(4))) unsigned short u16x4;

#define MFMA_BF16(a,b,c) __builtin_amdgcn_mfma_f32_16x16x32_bf16((a),(b),(c),0,0,0)

#define BATCH 2
#define SEQ   2048
#define DM    2048
#define NH    16
#define HD    128
#define MR    4096   /* BATCH*SEQ */

__device__ __forceinline__ u16 f2bf(float f){
  union{float f; unsigned u;} v; v.f = f;
  unsigned r = v.u + 0x7FFFu + ((v.u >> 16) & 1u);
  return (u16)(r >> 16);
}
__device__ __forceinline__ float bf2f(u16 h){
  union{unsigned u; float f;} v; v.u = ((unsigned)h) << 16;
  return v.f;
}
__device__ __forceinline__ void gll16(const void* g, void* l){
  __builtin_amdgcn_global_load_lds(
      (const __attribute__((address_space(1))) void*)g,
      (__attribute__((address_space(3))) void*)l, 16, 0, 0);
}

// ---------------------------------------------------------------- split fp32 -> (hi,lo) bf16
__global__ __launch_bounds__(256) void k_split(const float* __restrict__ in,
                                               u16* __restrict__ oh, u16* __restrict__ ol, int n4){
  int gid = blockIdx.x*256 + threadIdx.x;
  if (gid >= n4) return;
  float4 x = ((const float4*)in)[gid];
  u16 h0=f2bf(x.x), h1=f2bf(x.y), h2=f2bf(x.z), h3=f2bf(x.w);
  u16x4 vh = {h0,h1,h2,h3};
  u16x4 vl = {f2bf(x.x-bf2f(h0)), f2bf(x.y-bf2f(h1)), f2bf(x.z-bf2f(h2)), f2bf(x.w-bf2f(h3))};
  ((u16x4*)oh)[gid]=vh; ((u16x4*)ol)[gid]=vl;
}

// ---------------------------------------------------------------- W[K][N] -> Wt(hi/lo)[N][K] bf16
__global__ __launch_bounds__(256) void k_twsplit(const float* __restrict__ W,
                                                 u16* __restrict__ Th, u16* __restrict__ Tl){
  __shared__ float T[64][65];
  int n0 = blockIdx.x*64, k0 = blockIdx.y*64;
  int t = threadIdx.x;
  int r = t>>2, c = (t&3)*16;
  const float* src = W + (size_t)(k0+r)*DM + n0 + c;
  #pragma unroll
  for (int j=0;j<4;j++){
    float4 v = *(const float4*)(src + 4*j);
    T[r][c+4*j+0]=v.x; T[r][c+4*j+1]=v.y; T[r][c+4*j+2]=v.z; T[r][c+4*j+3]=v.w;
  }
  __syncthreads();
  int nr = t>>2, kc = (t&3)*16;
  size_t ob = (size_t)(n0+nr)*DM + k0 + kc;
  #pragma unroll
  for (int j=0;j<16;j+=4){
    u16x4 vh, vl;
    #pragma unroll
    for (int q=0;q<4;q++){
      float xv = T[kc+j+q][nr];
      u16 hh = f2bf(xv);
      vh[q]=hh; vl[q]=f2bf(xv - bf2f(hh));
    }
    *(u16x4*)(Th+ob+j)=vh; *(u16x4*)(Tl+ob+j)=vl;
  }
}

// ---------------------------------------------------------------- split GEMM: C = (Ah+Al)@(Bh+Bl)^T + bias
// A: [M][K] bf16 pair, B: [N][K] bf16 pair (pre-transposed weights), C: [M][N] fp32
__global__ __launch_bounds__(256) void k_gemm_split(
    const u16* __restrict__ Ah, const u16* __restrict__ Al,
    const u16* __restrict__ Bh, const u16* __restrict__ Bl,
    const float* __restrict__ bias, float* __restrict__ C,
    int M, int N, int K)
{
  __shared__ u16 sAh[128*32], sAl[128*32], sBh[128*32], sBl[128*32];
  const int tid = threadIdx.x;
  const int lane = tid & 63;
  const int w = tid >> 6;
  const int wr = w >> 1, wc = w & 1;
  const int bm = blockIdx.y * 128;
  const int bn = blockIdx.x * 128;

  // staging geometry: tile = [128 rows][64 B], wave w covers bytes [w*2048, w*2048+2048)
  const int off0 = w*2048 + lane*16;
  const int r0 = off0 >> 6, cb0 = off0 & 63;
  const int sc0 = cb0 ^ ((r0 & 3) << 4);
  const int off1 = off0 + 1024;
  const int r1 = off1 >> 6, cb1 = off1 & 63;
  const int sc1 = cb1 ^ ((r1 & 3) << 4);

  fx4 acc[4][4] = {};

  for (int k0 = 0; k0 < K; k0 += 32){
    __syncthreads();
    size_t aoff0 = (size_t)(bm + r0)*K + k0 + (sc0>>1);
    size_t aoff1 = (size_t)(bm + r1)*K + k0 + (sc1>>1);
    size_t boff0 = (size_t)(bn + r0)*K + k0 + (sc0>>1);
    size_t boff1 = (size_t)(bn + r1)*K + k0 + (sc1>>1);
    gll16(Ah + aoff0, sAh + w*1024);
    gll16(Ah + aoff1, sAh + w*1024 + 512);
    gll16(Al + aoff0, sAl + w*1024);
    gll16(Al + aoff1, sAl + w*1024 + 512);
    gll16(Bh + boff0, sBh + w*1024);
    gll16(Bh + boff1, sBh + w*1024 + 512);
    gll16(Bl + boff0, sBl + w*1024);
    gll16(Bl + boff1, sBl + w*1024 + 512);
    __syncthreads();

    const int cA = (lane>>4)<<4;
    bfx8 fah[4], fal[4], fbh[4], fbl[4];
    #pragma unroll
    for (int m=0;m<4;m++){
      int row = wr*64 + m*16 + (lane&15);
      int ad = row*64 + (cA ^ ((row&3)<<4));
      fah[m] = *(const bfx8*)((const char*)sAh + ad);
      fal[m] = *(const bfx8*)((const char*)sAl + ad);
    }
    #pragma unroll
    for (int n=0;n<4;n++){
      int row = wc*64 + n*16 + (lane&15);
      int ad = row*64 + (cA ^ ((row&3)<<4));
      fbh[n] = *(const bfx8*)((const char*)sBh + ad);
      fbl[n] = *(const bfx8*)((const char*)sBl + ad);
    }
    #pragma unroll
    for (int m=0;m<4;m++){
      #pragma unroll
      for (int n=0;n<4;n++){
        acc[m][n] = MFMA_BF16(fah[m], fbh[n], acc[m][n]);
        acc[m][n] = MFMA_BF16(fal[m], fbh[n], acc[m][n]);
        acc[m][n] = MFMA_BF16(fah[m], fbl[n], acc[m][n]);
      }
    }
  }

  #pragma unroll
  for (int m=0;m<4;m++){
    #pragma unroll
    for (int n=0;n<4;n++){
      int col = bn + wc*64 + n*16 + (lane&15);
      float bc = bias[col];
      #pragma unroll
      for (int r=0;r<4;r++){
        int row = bm + wr*64 + m*16 + ((lane>>4)<<2) + r;
        C[(size_t)row*N + col] = acc[m][n][r] + bc;
      }
    }
  }
}

// ---------------------------------------------------------------- rope + scale + cast, (B,N,D) -> (B,H,N,HD) bf16
__global__ __launch_bounds__(256) void k_rope(const float* __restrict__ in,
                                              const float* __restrict__ cs, const float* __restrict__ sn,
                                              u16* __restrict__ out, float qscale){
  int gid = blockIdx.x*256 + threadIdx.x;  // 4 elems each
  int base = gid*4;
  int row = base >> 11;        // b*SEQ + n
  int col = base & 2047;
  int b = row >> 11, n = row & 2047;
  int h = col >> 7,  d = col & 127;
  float4 x = *(const float4*)(in + (size_t)row*DM + col);
  float4 c = *(const float4*)(cs + n*HD + d);
  float4 s = *(const float4*)(sn + n*HD + d);
  float x0=x.x*qscale, x1=x.y*qscale, x2=x.z*qscale, x3=x.w*qscale;
  float y0 = x0*c.x - x1*s.x;
  float y1 = x1*c.y + x0*s.y;
  float y2 = x2*c.z - x3*s.z;
  float y3 = x3*c.w + x2*s.w;
  u16x4 o = {f2bf(y0), f2bf(y1), f2bf(y2), f2bf(y3)};
  *(u16x4*)(out + ((size_t)((b*NH+h)*SEQ + n)*HD + d)) = o;
}

// ---------------------------------------------------------------- v: (B,N,D) fp32 -> (B,H,HD,N) bf16 (transposed)
__global__ __launch_bounds__(256) void k_vt(const float* __restrict__ in, u16* __restrict__ vt){
  __shared__ float T[64][129];
  int bid = blockIdx.x;
  int nt = bid & 31, h = (bid>>5)&15, b = bid>>9;
  int n0 = nt*64;
  int t = threadIdx.x;
  int r = t>>2, c = (t&3)*32;
  const float* src = in + (size_t)(b*SEQ + n0 + r)*DM + h*HD + c;
  #pragma unroll
  for (int j=0;j<8;j++){
    float4 v = *(const float4*)(src + 4*j);
    T[r][c+4*j+0]=v.x; T[r][c+4*j+1]=v.y; T[r][c+4*j+2]=v.z; T[r][c+4*j+3]=v.w;
  }
  __syncthreads();
  int d = t>>1, half = t&1;
  u16* dst = vt + (size_t)((b*NH+h)*HD + d)*SEQ + n0 + half*32;
  #pragma unroll
  for (int j=0;j<32;j+=4){
    u16x4 o;
    #pragma unroll
    for (int q=0;q<4;q++) o[q] = f2bf(T[half*32+j+q][d]);
    *(u16x4*)(dst + j) = o;
  }
}

// ---------------------------------------------------------------- flash attention
// Q,K: (B,H,N,HD) bf16 (q pre-scaled by 1/HD); Vt: (B,H,HD,N) bf16; O: (B,N,D) fp32
__global__ __launch_bounds__(256) void k_flash(const u16* __restrict__ Q, const u16* __restrict__ Kb,
                                               const u16* __restrict__ Vt, float* __restrict__ O){
  __shared__ u16 sK[64*128];     // [kk][d], 256B rows, swizzled
  __shared__ u16 sV[128*64];     // [d][kk], 128B rows, swizzled
  __shared__ u16 sP[4][32*64];   // per-wave [q][kk], swizzled
  const int tid = threadIdx.x, lane = tid & 63, w = tid>>6;
  const int bid = blockIdx.x;
  const int qt = bid & 15, h = (bid>>4)&15, b = bid>>8;
  const int bh = b*NH + h;
  const int qbase = qt*128 + w*32;
  const float L2E = 1.4426950408889634f;

  // Q fragments (held in registers for the whole kernel)
  bfx8 qa[2][4];
  #pragma unroll
  for (int m=0;m<2;m++){
    int qrow = qbase + m*16 + (lane&15);
    const u16* qp = Q + ((size_t)bh*SEQ + qrow)*HD + ((lane>>4)<<3);
    #pragma unroll
    for (int ks=0;ks<4;ks++)
      qa[m][ks] = *(const bfx8*)(qp + ks*32);
  }

  fx4 accO[2][8] = {};
  float mrow[2][4], lrow[2][4];
  #pragma unroll
  for (int m=0;m<2;m++)
    #pragma unroll
    for (int r=0;r<4;r++){ mrow[m][r] = -1e30f; lrow[m][r] = 0.f; }

  u16* pb = sP[w];

  for (int kv0 = 0; kv0 < SEQ; kv0 += 64){
    __syncthreads();
    #pragma unroll
    for (int i=0;i<4;i++){
      int off = w*4096 + i*1024 + lane*16;
      int kr = off>>8, kc = off&255;
      int kcs = kc ^ ((kr&7)<<4);
      gll16(Kb + ((size_t)bh*SEQ + kv0 + kr)*HD + (kcs>>1), sK + w*2048 + i*512);
      int vr = off>>7, vc = off&127;
      int vcs = vc ^ ((vr&7)<<4);
      gll16(Vt + ((size_t)bh*HD + vr)*SEQ + kv0 + (vcs>>1), sV + w*2048 + i*512);
    }
    __syncthreads();

    // S = Q @ K^T  (32 q-rows x 64 kk-cols per wave)
    fx4 accS[2][4] = {};
    #pragma unroll
    for (int ks=0;ks<4;ks++){
      bfx8 kf[4];
      #pragma unroll
      for (int n=0;n<4;n++){
        int row = n*16 + (lane&15);
        int cb = ks*64 + ((lane>>4)<<4);
        int ad = row*256 + (cb ^ ((row&7)<<4));
        kf[n] = *(const bfx8*)((const char*)sK + ad);
      }
      #pragma unroll
      for (int m=0;m<2;m++)
        #pragma unroll
        for (int n=0;n<4;n++)
          accS[m][n] = MFMA_BF16(qa[m][ks], kf[n], accS[m][n]);
    }

    // online softmax per q-row
    #pragma unroll
    for (int m=0;m<2;m++){
      #pragma unroll
      for (int r=0;r<4;r++){
        float pm = fmaxf(fmaxf(accS[m][0][r], accS[m][1][r]),
                         fmaxf(accS[m][2][r], accS[m][3][r]));
        pm = fmaxf(pm, __shfl_xor(pm, 1, 64));
        pm = fmaxf(pm, __shfl_xor(pm, 2, 64));
        pm = fmaxf(pm, __shfl_xor(pm, 4, 64));
        pm = fmaxf(pm, __shfl_xor(pm, 8, 64));
        float mo = mrow[m][r];
        float mn = fmaxf(mo, pm);
        float al = exp2f((mo - mn) * L2E);
        float ps = 0.f;
        #pragma unroll
        for (int n=0;n<4;n++){
          float p = exp2f((accS[m][n][r] - mn) * L2E);
          accS[m][n][r] = p;
          ps += p;
        }
        ps += __shfl_xor(ps, 1, 64);
        ps += __shfl_xor(ps, 2, 64);
        ps += __shfl_xor(ps, 4, 64);
        ps += __shfl_xor(ps, 8, 64);
        lrow[m][r] = lrow[m][r]*al + ps;
        mrow[m][r] = mn;
        #pragma unroll
        for (int nn=0;nn<8;nn++) accO[m][nn][r] *= al;
      }
    }

    // P -> bf16 -> per-wave LDS (swizzled)
    #pragma unroll
    for (int m=0;m<2;m++)
      #pragma unroll
      for (int n=0;n<4;n++)
        #pragma unroll
        for (int r=0;r<4;r++){
          int row = m*16 + ((lane>>4)<<2) + r;
          int cb = (n*16 + (lane&15))*2;
          int ad = row*128 + (cb ^ ((row&7)<<4));
          *(u16*)((char*)pb + ad) = f2bf(accS[m][n][r]);
        }

    // O += P @ V
    #pragma unroll
    for (int ks=0;ks<2;ks++){
      bfx8 pa[2];
      #pragma unroll
      for (int m=0;m<2;m++){
        int row = m*16 + (lane&15);
        int cb = ks*64 + ((lane>>4)<<4);
        int ad = row*128 + (cb ^ ((row&7)<<4));
        pa[m] = *(const bfx8*)((const char*)pb + ad);
      }
      #pragma unroll
      for (int nn=0;nn<8;nn++){
        int row = nn*16 + (lane&15);
        int cb = ks*64 + ((lane>>4)<<4);
        int ad = row*128 + (cb ^ ((row&7)<<4));
        bfx8 vf = *(const bfx8*)((const char*)sV + ad);
        #pragma unroll
        for (int m=0;m<2;m++)
          accO[m][nn] = MFMA_BF16(pa[m], vf, accO[m][nn]);
      }
    }
  }

  // write O / l to (B,N,D)
  #pragma unroll
  for (int m=0;m<2;m++){
    #pragma unroll
    for (int r=0;r<4;r++){
      float inv = 1.0f / lrow[m][r];
      int qrow = qbase + m*16 + ((lane>>4)<<2) + r;
      float* op = O + ((size_t)(b*SEQ + qrow))*DM + h*HD + (lane&15);
      #pragma unroll
      for (int nn=0;nn<8;nn++)
        op[nn*16] = accO[m][nn][r] * inv;
    }
  }
}

// ----------------------------------------------------------------
extern "C" void kernel_launch(void* const* d_in, const int* in_sizes, int n_in,
                              void* d_out, int out_size, void* d_ws, size_t ws_size,
                              hipStream_t stream){
  (void)in_sizes; (void)n_in; (void)out_size; (void)ws_size;
  const float* x  = (const float*)d_in[0];
  const float* cs = (const float*)d_in[1];
  const float* sn = (const float*)d_in[2];
  const float* Wq = (const float*)d_in[3];
  const float* bq = (const float*)d_in[4];
  const float* Wk = (const float*)d_in[5];
  const float* bk = (const float*)d_in[6];
  const float* Wv = (const float*)d_in[7];
  const float* bv = (const float*)d_in[8];
  const float* Wo = (const float*)d_in[9];
  const float* bo = (const float*)d_in[10];
  float* out = (float*)d_out;

  char* ws = (char*)d_ws;
  const size_t SZ16M = 16777216;
  u16* xh  = (u16*)(ws);
  u16* xl  = (u16*)(ws + SZ16M);
  u16* wth = (u16*)(ws + 2*SZ16M);
  u16* wtl = (u16*)(ws + 2*SZ16M + 8388608);
  u16* qb  = (u16*)(ws + 3*SZ16M);
  u16* kb  = (u16*)(ws + 4*SZ16M);
  u16* vt  = (u16*)(ws + 5*SZ16M);
  float* tmp = (float*)(ws + 6*SZ16M);   // 32 MiB; total = 128 MiB

  const float rope_qscale = 1.0f/128.0f;   // scale^2 folded into q (rope is linear)

  k_split<<<8192,256,0,stream>>>(x, xh, xl, 2097152);

  // Q
  k_twsplit<<<dim3(32,32),256,0,stream>>>(Wq, wth, wtl);
  k_gemm_split<<<dim3(16,32),256,0,stream>>>(xh,xl,wth,wtl,bq,tmp,MR,DM,DM);
  k_rope<<<8192,256,0,stream>>>(tmp, cs, sn, qb, rope_qscale);
  // K
  k_twsplit<<<dim3(32,32),256,0,stream>>>(Wk, wth, wtl);
  k_gemm_split<<<dim3(16,32),256,0,stream>>>(xh,xl,wth,wtl,bk,tmp,MR,DM,DM);
  k_rope<<<8192,256,0,stream>>>(tmp, cs, sn, kb, 1.0f);
  // V
  k_twsplit<<<dim3(32,32),256,0,stream>>>(Wv, wth, wtl);
  k_gemm_split<<<dim3(16,32),256,0,stream>>>(xh,xl,wth,wtl,bv,tmp,MR,DM,DM);
  k_vt<<<1024,256,0,stream>>>(tmp, vt);

  // attention -> tmp (B,N,D) fp32
  k_flash<<<512,256,0,stream>>>(qb, kb, vt, tmp);

  // output projection (reuse qb/kb as o hi/lo)
  k_split<<<8192,256,0,stream>>>(tmp, qb, kb, 2097152);
  k_twsplit<<<dim3(32,32),256,0,stream>>>(Wo, wth, wtl);
  k_gemm_split<<<dim3(16,32),256,0,stream>>>(qb,kb,wth,wtl,bo,out,MR,DM,DM);
}

// Round 3
// 631.370 us; speedup vs baseline: 1.2061x; 1.2061x over previous
//
#include <hip/hip_runtime.h>

typedef unsigned short u16;
typedef __attribute__((ext_vector_type(8))) short bfx8;
typedef __attribute__((ext_vector_type(4))) float fx4;
typedef __attribute__((ext_vector_type(4))) unsigned short u16x4;

#define MFMA_BF16(a,b,c) __builtin_amdgcn_mfma_f32_16x16x32_bf16((a),(b),(c),0,0,0)

#define BATCH 2
#define SEQ   2048
#define DM    2048
#define NH    16
#define HD    128
#define MR    4096   /* BATCH*SEQ */

__device__ __forceinline__ u16 f2bf(float f){
  union{float f; unsigned u;} v; v.f = f;
  unsigned r = v.u + 0x7FFFu + ((v.u >> 16) & 1u);
  return (u16)(r >> 16);
}
__device__ __forceinline__ float bf2f(u16 h){
  union{unsigned u; float f;} v; v.u = ((unsigned)h) << 16;
  return v.f;
}
__device__ __forceinline__ unsigned cvtpk(float lo, float hi){
  unsigned r;
  asm("v_cvt_pk_bf16_f32 %0, %1, %2" : "=v"(r) : "v"(lo), "v"(hi));
  return r;
}
__device__ __forceinline__ void gll16(const void* g, void* l){
  __builtin_amdgcn_global_load_lds(
      (const __attribute__((address_space(1))) void*)g,
      (__attribute__((address_space(3))) void*)l, 16, 0, 0);
}

// ---------------------------------------------------------------- split fp32 -> (hi,lo) bf16
__global__ __launch_bounds__(256) void k_split(const float* __restrict__ in,
                                               u16* __restrict__ oh, u16* __restrict__ ol, int n4){
  int gid = blockIdx.x*256 + threadIdx.x;
  if (gid >= n4) return;
  float4 x = ((const float4*)in)[gid];
  u16 h0=f2bf(x.x), h1=f2bf(x.y), h2=f2bf(x.z), h3=f2bf(x.w);
  u16x4 vh = {h0,h1,h2,h3};
  u16x4 vl = {f2bf(x.x-bf2f(h0)), f2bf(x.y-bf2f(h1)), f2bf(x.z-bf2f(h2)), f2bf(x.w-bf2f(h3))};
  ((u16x4*)oh)[gid]=vh; ((u16x4*)ol)[gid]=vl;
}

// ---------------------------------------------------------------- W[K][N] -> Wt(hi/lo)[N][K] bf16
__global__ __launch_bounds__(256) void k_twsplit(const float* __restrict__ W,
                                                 u16* __restrict__ Th, u16* __restrict__ Tl){
  __shared__ float T[64][65];
  int n0 = blockIdx.x*64, k0 = blockIdx.y*64;
  int t = threadIdx.x;
  int r = t>>2, c = (t&3)*16;
  const float* src = W + (size_t)(k0+r)*DM + n0 + c;
  #pragma unroll
  for (int j=0;j<4;j++){
    float4 v = *(const float4*)(src + 4*j);
    T[r][c+4*j+0]=v.x; T[r][c+4*j+1]=v.y; T[r][c+4*j+2]=v.z; T[r][c+4*j+3]=v.w;
  }
  __syncthreads();
  int nr = t>>2, kc = (t&3)*16;
  size_t ob = (size_t)(n0+nr)*DM + k0 + kc;
  #pragma unroll
  for (int j=0;j<16;j+=4){
    u16x4 vh, vl;
    #pragma unroll
    for (int q=0;q<4;q++){
      float xv = T[kc+j+q][nr];
      u16 hh = f2bf(xv);
      vh[q]=hh; vl[q]=f2bf(xv - bf2f(hh));
    }
    *(u16x4*)(Th+ob+j)=vh; *(u16x4*)(Tl+ob+j)=vl;
  }
}

// ---------------------------------------------------------------- split GEMM: C = (Ah+Al)@(Bh+Bl)^T + bias
__global__ __launch_bounds__(256) void k_gemm_split(
    const u16* __restrict__ Ah, const u16* __restrict__ Al,
    const u16* __restrict__ Bh, const u16* __restrict__ Bl,
    const float* __restrict__ bias, float* __restrict__ C,
    int M, int N, int K)
{
  __shared__ u16 sAh[128*32], sAl[128*32], sBh[128*32], sBl[128*32];
  const int tid = threadIdx.x;
  const int lane = tid & 63;
  const int w = tid >> 6;
  const int wr = w >> 1, wc = w & 1;
  const int bm = blockIdx.y * 128;
  const int bn = blockIdx.x * 128;

  const int off0 = w*2048 + lane*16;
  const int r0 = off0 >> 6, cb0 = off0 & 63;
  const int sc0 = cb0 ^ ((r0 & 3) << 4);
  const int off1 = off0 + 1024;
  const int r1 = off1 >> 6, cb1 = off1 & 63;
  const int sc1 = cb1 ^ ((r1 & 3) << 4);

  fx4 acc[4][4] = {};

  for (int k0 = 0; k0 < K; k0 += 32){
    __syncthreads();
    size_t aoff0 = (size_t)(bm + r0)*K + k0 + (sc0>>1);
    size_t aoff1 = (size_t)(bm + r1)*K + k0 + (sc1>>1);
    size_t boff0 = (size_t)(bn + r0)*K + k0 + (sc0>>1);
    size_t boff1 = (size_t)(bn + r1)*K + k0 + (sc1>>1);
    gll16(Ah + aoff0, sAh + w*1024);
    gll16(Ah + aoff1, sAh + w*1024 + 512);
    gll16(Al + aoff0, sAl + w*1024);
    gll16(Al + aoff1, sAl + w*1024 + 512);
    gll16(Bh + boff0, sBh + w*1024);
    gll16(Bh + boff1, sBh + w*1024 + 512);
    gll16(Bl + boff0, sBl + w*1024);
    gll16(Bl + boff1, sBl + w*1024 + 512);
    __syncthreads();

    const int cA = (lane>>4)<<4;
    bfx8 fah[4], fal[4], fbh[4], fbl[4];
    #pragma unroll
    for (int m=0;m<4;m++){
      int row = wr*64 + m*16 + (lane&15);
      int ad = row*64 + (cA ^ ((row&3)<<4));
      fah[m] = *(const bfx8*)((const char*)sAh + ad);
      fal[m] = *(const bfx8*)((const char*)sAl + ad);
    }
    #pragma unroll
    for (int n=0;n<4;n++){
      int row = wc*64 + n*16 + (lane&15);
      int ad = row*64 + (cA ^ ((row&3)<<4));
      fbh[n] = *(const bfx8*)((const char*)sBh + ad);
      fbl[n] = *(const bfx8*)((const char*)sBl + ad);
    }
    #pragma unroll
    for (int m=0;m<4;m++){
      #pragma unroll
      for (int n=0;n<4;n++){
        acc[m][n] = MFMA_BF16(fah[m], fbh[n], acc[m][n]);
        acc[m][n] = MFMA_BF16(fal[m], fbh[n], acc[m][n]);
        acc[m][n] = MFMA_BF16(fah[m], fbl[n], acc[m][n]);
      }
    }
  }

  #pragma unroll
  for (int m=0;m<4;m++){
    #pragma unroll
    for (int n=0;n<4;n++){
      int col = bn + wc*64 + n*16 + (lane&15);
      float bc = bias[col];
      #pragma unroll
      for (int r=0;r<4;r++){
        int row = bm + wr*64 + m*16 + ((lane>>4)<<2) + r;
        C[(size_t)row*N + col] = acc[m][n][r] + bc;
      }
    }
  }
}

// ---------------------------------------------------------------- rope + scale + cast, (B,N,D) -> (B,H,N,HD) bf16
__global__ __launch_bounds__(256) void k_rope(const float* __restrict__ in,
                                              const float* __restrict__ cs, const float* __restrict__ sn,
                                              u16* __restrict__ out, float qscale){
  int gid = blockIdx.x*256 + threadIdx.x;
  int base = gid*4;
  int row = base >> 11;
  int col = base & 2047;
  int b = row >> 11, n = row & 2047;
  int h = col >> 7,  d = col & 127;
  float4 x = *(const float4*)(in + (size_t)row*DM + col);
  float4 c = *(const float4*)(cs + n*HD + d);
  float4 s = *(const float4*)(sn + n*HD + d);
  float x0=x.x*qscale, x1=x.y*qscale, x2=x.z*qscale, x3=x.w*qscale;
  float y0 = x0*c.x - x1*s.x;
  float y1 = x1*c.y + x0*s.y;
  float y2 = x2*c.z - x3*s.z;
  float y3 = x3*c.w + x2*s.w;
  u16x4 o = {f2bf(y0), f2bf(y1), f2bf(y2), f2bf(y3)};
  *(u16x4*)(out + ((size_t)((b*NH+h)*SEQ + n)*HD + d)) = o;
}

// ---------------------------------------------------------------- v: (B,N,D) fp32 -> (B,H,HD,N) bf16 (transposed)
__global__ __launch_bounds__(256) void k_vt(const float* __restrict__ in, u16* __restrict__ vt){
  __shared__ float T[64][129];
  int bid = blockIdx.x;
  int nt = bid & 31, h = (bid>>5)&15, b = bid>>9;
  int n0 = nt*64;
  int t = threadIdx.x;
  int r = t>>2, c = (t&3)*32;
  const float* src = in + (size_t)(b*SEQ + n0 + r)*DM + h*HD + c;
  #pragma unroll
  for (int j=0;j<8;j++){
    float4 v = *(const float4*)(src + 4*j);
    T[r][c+4*j+0]=v.x; T[r][c+4*j+1]=v.y; T[r][c+4*j+2]=v.z; T[r][c+4*j+3]=v.w;
  }
  __syncthreads();
  int d = t>>1, half = t&1;
  u16* dst = vt + (size_t)((b*NH+h)*HD + d)*SEQ + n0 + half*32;
  #pragma unroll
  for (int j=0;j<32;j+=4){
    u16x4 o;
    #pragma unroll
    for (int q=0;q<4;q++) o[q] = f2bf(T[half*32+j+q][d]);
    *(u16x4*)(dst + j) = o;
  }
}

// ---------------------------------------------------------------- flash attention (swapped-operand, in-register P)
// Q: (B,H,N,HD) bf16 pre-scaled by log2(e)/HD; K: (B,H,N,HD) bf16; Vt: (B,H,HD,N) bf16; O: (B,N,D) fp32
__global__ __launch_bounds__(256) void k_flash(const u16* __restrict__ Q, const u16* __restrict__ Kb,
                                               const u16* __restrict__ Vt, float* __restrict__ O){
  __shared__ u16 sK[2][64*128];   // [kk][d], 256B rows, XOR-swizzled
  __shared__ u16 sV[2][128*64];   // [d][kk], 128B rows, XOR-swizzled
  const int tid = threadIdx.x, lane = tid & 63, w = tid >> 6;
  const int bid = blockIdx.x;
  const int qt = bid & 31, h = (bid>>5)&15, b = bid>>9;
  const int bh = b*NH + h;
  const int qb0 = qt*64;
  const int g = lane >> 4, qi = lane & 15;

  // Q as B-fragment: lane holds col q = qi, d-slice g*8 (+ks*32). 16 q-rows per wave.
  bfx8 qf[4];
  {
    const u16* qp = Q + ((size_t)bh*SEQ + qb0 + w*16 + qi)*HD + g*8;
    #pragma unroll
    for (int ks=0; ks<4; ++ks) qf[ks] = *(const bfx8*)(qp + ks*32);
  }

  // staging source offsets (pre-swizzled global source, linear LDS dest)
  size_t kbase[4], vbase[4];
  #pragma unroll
  for (int i=0;i<4;i++){
    int off = w*4096 + i*1024 + lane*16;
    int kr = off>>8, kc = off&255;
    int kcs = kc ^ ((kr&7)<<4);
    kbase[i] = ((size_t)bh*SEQ + kr)*HD + (kcs>>1);
    int vr = off>>7, vc = off&127;
    int vcs = vc ^ ((vr&7)<<4);
    vbase[i] = ((size_t)bh*HD + vr)*SEQ + (vcs>>1);
  }

#define STG(bf_, kv_, i_) \
    gll16(Kb + kbase[i_] + (size_t)(kv_)*HD, &sK[bf_][w*2048 + i_*512]); \
    gll16(Vt + vbase[i_] + (kv_),            &sV[bf_][w*2048 + i_*512]);
#define STAGE(bf_, kv_) do { STG(bf_,kv_,0) STG(bf_,kv_,1) STG(bf_,kv_,2) STG(bf_,kv_,3) } while(0)

  fx4 accO[8] = {};                 // O^T: row d = nn*16+g*4+r, col q = qi
  float m_run = -1e30f, l_run = 0.f;

  STAGE(0, 0);
  __syncthreads();
  int buf = 0;

  for (int t=0; t<32; ++t){
    if (t < 31) STAGE(buf^1, (t+1)*64);
    const u16* sk = sK[buf];
    const u16* sv = sV[buf];

    // S^T = K @ Q^T : 64 kk-rows x 16 q-cols
    fx4 st[4] = {};
    #pragma unroll
    for (int ks=0; ks<4; ++ks){
      bfx8 kf[4];
      #pragma unroll
      for (int n=0;n<4;n++){
        int row = n*16 + qi;
        int cb = ks*64 + g*16;
        kf[n] = *(const bfx8*)((const char*)sk + row*256 + (cb ^ ((row&7)<<4)));
      }
      #pragma unroll
      for (int n=0;n<4;n++) st[n] = MFMA_BF16(kf[n], qf[ks], st[n]);
    }

    // online softmax in log2 domain; lane owns q=qi, holds kk = n*16+g*4+r
    float pm = st[0][0];
    #pragma unroll
    for (int n=0;n<4;n++)
      #pragma unroll
      for (int r=0;r<4;r++) pm = fmaxf(pm, st[n][r]);
    pm = fmaxf(pm, __shfl_xor(pm, 16, 64));
    pm = fmaxf(pm, __shfl_xor(pm, 32, 64));
    if (!__all(pm <= m_run + 11.0f)){      // T13 defer-max
      float mn = fmaxf(m_run, pm);
      float al = exp2f(m_run - mn);
      l_run *= al;
      #pragma unroll
      for (int nn=0;nn<8;nn++) accO[nn] = accO[nn]*al;
      m_run = mn;
    }
    float ps = 0.f;
    #pragma unroll
    for (int n=0;n<4;n++)
      #pragma unroll
      for (int r=0;r<4;r++){
        float p = exp2f(st[n][r] - m_run);
        st[n][r] = p;
        ps += p;
      }
    ps += __shfl_xor(ps, 16, 64);
    ps += __shfl_xor(ps, 32, 64);
    l_run += ps;

    // pack P rows to bf16 pairs; lane (g',qi) reg pk{n}{l,h} = P[qi][n*16+g'*4+{0,1 | 2,3}]
    int pk0l = (int)cvtpk(st[0][0], st[0][1]), pk0h = (int)cvtpk(st[0][2], st[0][3]);
    int pk1l = (int)cvtpk(st[1][0], st[1][1]), pk1h = (int)cvtpk(st[1][2], st[1][3]);
    int pk2l = (int)cvtpk(st[2][0], st[2][1]), pk2h = (int)cvtpk(st[2][2], st[2][3]);
    int pk3l = (int)cvtpk(st[3][0], st[3][1]), pk3h = (int)cvtpk(st[3][2], st[3][3]);

    const int s0 = qi + 16*((2*g)&3);      // src lane for kk block ks*32+g*8+{0..3}
    const int s1 = qi + 16*((2*g+1)&3);    // src lane for kk block ks*32+g*8+{4..7}
    const bool hi = (g>>1) != 0;           // DEST selector: n = 2ks + (g>>1)

    // O^T += V^T @ P^T. B-frag: lane needs P[qi][ks*32+g*8+0..8).
    // Both n-candidates are shuffled; select at DEST by hi (src-side select was the r2 bug).
    #pragma unroll
    for (int ks=0; ks<2; ++ks){
      int cl0 = ks ? pk2l : pk0l;   // n = 2ks,   elems {0,1} of 4-block
      int ch0 = ks ? pk2h : pk0h;   // n = 2ks,   elems {2,3}
      int cl1 = ks ? pk3l : pk1l;   // n = 2ks+1, elems {0,1}
      int ch1 = ks ? pk3h : pk1h;   // n = 2ks+1, elems {2,3}
      int t00 = __shfl(cl0, s0, 64), t10 = __shfl(cl1, s0, 64);
      int t01 = __shfl(ch0, s0, 64), t11 = __shfl(ch1, s0, 64);
      int t02 = __shfl(cl0, s1, 64), t12 = __shfl(cl1, s1, 64);
      int t03 = __shfl(ch0, s1, 64), t13 = __shfl(ch1, s1, 64);
      union { bfx8 v; int u[4]; } pv;
      pv.u[0] = hi ? t10 : t00;
      pv.u[1] = hi ? t11 : t01;
      pv.u[2] = hi ? t12 : t02;
      pv.u[3] = hi ? t13 : t03;
      #pragma unroll
      for (int nn=0;nn<8;nn++){
        int row = nn*16 + qi;
        int cb = ks*64 + g*16;
        bfx8 vf = *(const bfx8*)((const char*)sv + row*128 + (cb ^ ((row&7)<<4)));
        accO[nn] = MFMA_BF16(vf, pv.v, accO[nn]);
      }
    }
    __syncthreads();    // drains next-tile loads (vmcnt) + guards buf reuse
    buf ^= 1;
  }
#undef STAGE
#undef STG

  // epilogue: O^T regs -> LDS (swizzled) -> coalesced global
  float inv = 1.0f / l_run;
  float* ob = (float*)&sK[0][0];   // 64 q x 128 d x 4B = 32KB, aliases sK
  {
    int q = w*16 + qi;
    #pragma unroll
    for (int nn=0;nn<8;nn++)
      #pragma unroll
      for (int r=0;r<4;r++){
        int d = nn*16 + g*4 + r;
        *(float*)((char*)ob + q*512 + ((d*4) ^ ((q&7)<<4))) = accO[nn][r]*inv;
      }
  }
  __syncthreads();
  {
    int q2 = tid>>2, c0 = (tid&3)*32;
    float* dst = O + ((size_t)(b*SEQ + qb0 + q2))*DM + h*HD + c0;
    #pragma unroll
    for (int j=0;j<8;j++){
      int d0 = c0 + j*4;
      float4 v = *(const float4*)((const char*)ob + q2*512 + ((d0*4) ^ ((q2&7)<<4)));
      *(float4*)(dst + j*4) = v;
    }
  }
}

// ----------------------------------------------------------------
extern "C" void kernel_launch(void* const* d_in, const int* in_sizes, int n_in,
                              void* d_out, int out_size, void* d_ws, size_t ws_size,
                              hipStream_t stream){
  (void)in_sizes; (void)n_in; (void)out_size; (void)ws_size;
  const float* x  = (const float*)d_in[0];
  const float* cs = (const float*)d_in[1];
  const float* sn = (const float*)d_in[2];
  const float* Wq = (const float*)d_in[3];
  const float* bq = (const float*)d_in[4];
  const float* Wk = (const float*)d_in[5];
  const float* bk = (const float*)d_in[6];
  const float* Wv = (const float*)d_in[7];
  const float* bv = (const float*)d_in[8];
  const float* Wo = (const float*)d_in[9];
  const float* bo = (const float*)d_in[10];
  float* out = (float*)d_out;

  char* ws = (char*)d_ws;
  const size_t SZ16M = 16777216;
  u16* xh  = (u16*)(ws);
  u16* xl  = (u16*)(ws + SZ16M);
  u16* wth = (u16*)(ws + 2*SZ16M);
  u16* wtl = (u16*)(ws + 2*SZ16M + 8388608);
  u16* qb  = (u16*)(ws + 3*SZ16M);
  u16* kb  = (u16*)(ws + 4*SZ16M);
  u16* vt  = (u16*)(ws + 5*SZ16M);
  float* tmp = (float*)(ws + 6*SZ16M);

  // scale^2 = 1/HD and log2(e) folded into q (rope is linear)
  const float rope_qscale = 1.4426950408889634f/128.0f;

  k_split<<<8192,256,0,stream>>>(x, xh, xl, 2097152);

  // Q
  k_twsplit<<<dim3(32,32),256,0,stream>>>(Wq, wth, wtl);
  k_gemm_split<<<dim3(16,32),256,0,stream>>>(xh,xl,wth,wtl,bq,tmp,MR,DM,DM);
  k_rope<<<8192,256,0,stream>>>(tmp, cs, sn, qb, rope_qscale);
  // K
  k_twsplit<<<dim3(32,32),256,0,stream>>>(Wk, wth, wtl);
  k_gemm_split<<<dim3(16,32),256,0,stream>>>(xh,xl,wth,wtl,bk,tmp,MR,DM,DM);
  k_rope<<<8192,256,0,stream>>>(tmp, cs, sn, kb, 1.0f);
  // V
  k_twsplit<<<dim3(32,32),256,0,stream>>>(Wv, wth, wtl);
  k_gemm_split<<<dim3(16,32),256,0,stream>>>(xh,xl,wth,wtl,bv,tmp,MR,DM,DM);
  k_vt<<<1024,256,0,stream>>>(tmp, vt);

  // attention -> tmp (B,N,D) fp32
  k_flash<<<1024,256,0,stream>>>(qb, kb, vt, tmp);

  // output projection
  k_split<<<8192,256,0,stream>>>(tmp, qb, kb, 2097152);
  k_twsplit<<<dim3(32,32),256,0,stream>>>(Wo, wth, wtl);
  k_gemm_split<<<dim3(16,32),256,0,stream>>>(qb,kb,wth,wtl,bo,out,MR,DM,DM);
}

// Round 4
// 399.746 us; speedup vs baseline: 1.9050x; 1.5794x over previous
//
#include <hip/hip_runtime.h>

typedef unsigned short u16;
typedef __attribute__((ext_vector_type(8))) short bfx8;
typedef __attribute__((ext_vector_type(4))) float fx4;
typedef __attribute__((ext_vector_type(4))) unsigned short u16x4;

#define MFMA_BF16(a,b,c) __builtin_amdgcn_mfma_f32_16x16x32_bf16((a),(b),(c),0,0,0)

#define BATCH 2
#define SEQ   2048
#define DM    2048
#define NH    16
#define HD    128
#define MR    4096   /* BATCH*SEQ */

__device__ __forceinline__ u16 f2bf(float f){
  union{float f; unsigned u;} v; v.f = f;
  unsigned r = v.u + 0x7FFFu + ((v.u >> 16) & 1u);
  return (u16)(r >> 16);
}
__device__ __forceinline__ unsigned cvtpk(float lo, float hi){
  unsigned r;
  asm("v_cvt_pk_bf16_f32 %0, %1, %2" : "=v"(r) : "v"(lo), "v"(hi));
  return r;
}
__device__ __forceinline__ void gll16(const void* g, void* l){
  __builtin_amdgcn_global_load_lds(
      (const __attribute__((address_space(1))) void*)g,
      (__attribute__((address_space(3))) void*)l, 16, 0, 0);
}

// ---------------------------------------------------------------- fp32 -> bf16 cast (vectorized)
__global__ __launch_bounds__(256) void k_cast(const float* __restrict__ in,
                                              u16* __restrict__ o, int n4){
  int gid = blockIdx.x*256 + threadIdx.x;
  if (gid >= n4) return;
  float4 x = ((const float4*)in)[gid];
  u16x4 v = {f2bf(x.x), f2bf(x.y), f2bf(x.z), f2bf(x.w)};
  ((u16x4*)o)[gid] = v;
}

// ---------------------------------------------------------------- W[K][N] -> Wt[N][K] bf16
__global__ __launch_bounds__(256) void k_tw(const float* __restrict__ W, u16* __restrict__ Th){
  __shared__ float T[64][65];
  int n0 = blockIdx.x*64, k0 = blockIdx.y*64;
  int t = threadIdx.x;
  int r = t>>2, c = (t&3)*16;
  const float* src = W + (size_t)(k0+r)*DM + n0 + c;
  #pragma unroll
  for (int j=0;j<4;j++){
    float4 v = *(const float4*)(src + 4*j);
    T[r][c+4*j+0]=v.x; T[r][c+4*j+1]=v.y; T[r][c+4*j+2]=v.z; T[r][c+4*j+3]=v.w;
  }
  __syncthreads();
  int nr = t>>2, kc = (t&3)*16;
  size_t ob = (size_t)(n0+nr)*DM + k0 + kc;
  #pragma unroll
  for (int j=0;j<16;j+=4){
    u16x4 vh;
    #pragma unroll
    for (int q=0;q<4;q++) vh[q] = f2bf(T[kc+j+q][nr]);
    *(u16x4*)(Th+ob+j)=vh;
  }
}

// ---------------------------------------------------------------- GEMM: C = A@B^T + bias (bf16, BK=64)
// A: [M][K] bf16, B: [N][K] bf16, C: [M][N] fp32
__global__ __launch_bounds__(256) void k_gemm(
    const u16* __restrict__ A, const u16* __restrict__ B,
    const float* __restrict__ bias, float* __restrict__ C,
    int M, int N, int K)
{
  __shared__ u16 sA[128*64], sB[128*64];   // [128 rows][128 B], XOR-swizzled
  const int tid = threadIdx.x;
  const int lane = tid & 63;
  const int w = tid >> 6;
  const int g = lane >> 4, qi = lane & 15;
  const int wr = w >> 1, wc = w & 1;
  const int bm = blockIdx.y * 128;
  const int bn = blockIdx.x * 128;

  int r_[4], sc_[4];
  #pragma unroll
  for (int i=0;i<4;i++){
    int off = w*4096 + i*1024 + lane*16;
    int r = off>>7, cb = off&127;
    r_[i] = r; sc_[i] = (cb ^ ((r&7)<<4)) >> 1;
  }

  fx4 acc[4][4] = {};

  for (int k0 = 0; k0 < K; k0 += 64){
    __syncthreads();
    #pragma unroll
    for (int i=0;i<4;i++){
      gll16(A + (size_t)(bm + r_[i])*K + k0 + sc_[i], &sA[w*2048 + i*512]);
      gll16(B + (size_t)(bn + r_[i])*K + k0 + sc_[i], &sB[w*2048 + i*512]);
    }
    __syncthreads();

    #pragma unroll
    for (int kk=0;kk<2;kk++){
      const int cb = kk*64 + g*16;
      bfx8 fa[4], fb[4];
      #pragma unroll
      for (int m=0;m<4;m++){
        int row = wr*64 + m*16 + qi;
        fa[m] = *(const bfx8*)((const char*)sA + row*128 + (cb ^ ((row&7)<<4)));
      }
      #pragma unroll
      for (int n=0;n<4;n++){
        int row = wc*64 + n*16 + qi;
        fb[n] = *(const bfx8*)((const char*)sB + row*128 + (cb ^ ((row&7)<<4)));
      }
      #pragma unroll
      for (int m=0;m<4;m++)
        #pragma unroll
        for (int n=0;n<4;n++)
          acc[m][n] = MFMA_BF16(fa[m], fb[n], acc[m][n]);
    }
  }

  #pragma unroll
  for (int m=0;m<4;m++){
    #pragma unroll
    for (int n=0;n<4;n++){
      int col = bn + wc*64 + n*16 + qi;
      float bc = bias[col];
      #pragma unroll
      for (int r=0;r<4;r++){
        int row = bm + wr*64 + m*16 + g*4 + r;
        C[(size_t)row*N + col] = acc[m][n][r] + bc;
      }
    }
  }
}

// ---------------------------------------------------------------- rope + scale + cast, (B,N,D) -> (B,H,N,HD) bf16
__global__ __launch_bounds__(256) void k_rope(const float* __restrict__ in,
                                              const float* __restrict__ cs, const float* __restrict__ sn,
                                              u16* __restrict__ out, float qscale){
  int gid = blockIdx.x*256 + threadIdx.x;
  int base = gid*4;
  int row = base >> 11;
  int col = base & 2047;
  int b = row >> 11, n = row & 2047;
  int h = col >> 7,  d = col & 127;
  float4 x = *(const float4*)(in + (size_t)row*DM + col);
  float4 c = *(const float4*)(cs + n*HD + d);
  float4 s = *(const float4*)(sn + n*HD + d);
  float x0=x.x*qscale, x1=x.y*qscale, x2=x.z*qscale, x3=x.w*qscale;
  float y0 = x0*c.x - x1*s.x;
  float y1 = x1*c.y + x0*s.y;
  float y2 = x2*c.z - x3*s.z;
  float y3 = x3*c.w + x2*s.w;
  u16x4 o = {f2bf(y0), f2bf(y1), f2bf(y2), f2bf(y3)};
  *(u16x4*)(out + ((size_t)((b*NH+h)*SEQ + n)*HD + d)) = o;
}

// ---------------------------------------------------------------- v: (B,N,D) fp32 -> (B,H,HD,N) bf16 (transposed)
__global__ __launch_bounds__(256) void k_vt(const float* __restrict__ in, u16* __restrict__ vt){
  __shared__ float T[64][129];
  int bid = blockIdx.x;
  int nt = bid & 31, h = (bid>>5)&15, b = bid>>9;
  int n0 = nt*64;
  int t = threadIdx.x;
  int r = t>>2, c = (t&3)*32;
  const float* src = in + (size_t)(b*SEQ + n0 + r)*DM + h*HD + c;
  #pragma unroll
  for (int j=0;j<8;j++){
    float4 v = *(const float4*)(src + 4*j);
    T[r][c+4*j+0]=v.x; T[r][c+4*j+1]=v.y; T[r][c+4*j+2]=v.z; T[r][c+4*j+3]=v.w;
  }
  __syncthreads();
  int d = t>>1, half = t&1;
  u16* dst = vt + (size_t)((b*NH+h)*HD + d)*SEQ + n0 + half*32;
  #pragma unroll
  for (int j=0;j<32;j+=4){
    u16x4 o;
    #pragma unroll
    for (int q=0;q<4;q++) o[q] = f2bf(T[half*32+j+q][d]);
    *(u16x4*)(dst + j) = o;
  }
}

// ---------------------------------------------------------------- flash attention (swapped-operand, 2 q-blocks/wave)
// Q: (B,H,N,HD) bf16 pre-scaled by log2(e)/HD; K: (B,H,N,HD) bf16; Vt: (B,H,HD,N) bf16; O: (B,N,D) fp32
__global__ __launch_bounds__(256) void k_flash(const u16* __restrict__ Q, const u16* __restrict__ Kb,
                                               const u16* __restrict__ Vt, float* __restrict__ O){
  __shared__ union SM {
    struct { u16 k[2][64*128]; u16 v[2][128*64]; } s;   // 32KB + 32KB
    float ob[128*128];                                   // 64KB epilogue buffer
  } sm;
  const int tid = threadIdx.x, lane = tid & 63, w = tid >> 6;
  const int bid = blockIdx.x;
  const int qt = bid & 15, h = (bid>>4)&15, b = bid>>8;
  const int bh = b*NH + h;
  const int qb0 = qt*128;
  const int g = lane >> 4, qi = lane & 15;

  // Q as B-fragment, two q-column-blocks per wave (q = qb0 + w*32 + j*16 + qi)
  bfx8 qf[2][4];
  #pragma unroll
  for (int j=0;j<2;j++){
    const u16* qp = Q + ((size_t)bh*SEQ + qb0 + w*32 + j*16 + qi)*HD + g*8;
    #pragma unroll
    for (int ks=0; ks<4; ++ks) qf[j][ks] = *(const bfx8*)(qp + ks*32);
  }

  // staging source offsets (pre-swizzled global source, linear LDS dest)
  size_t kbase[4], vbase[4];
  #pragma unroll
  for (int i=0;i<4;i++){
    int off = w*4096 + i*1024 + lane*16;
    int kr = off>>8, kc = off&255;
    int kcs = kc ^ ((kr&7)<<4);
    kbase[i] = ((size_t)bh*SEQ + kr)*HD + (kcs>>1);
    int vr = off>>7, vc = off&127;
    int vcs = vc ^ ((vr&7)<<4);
    vbase[i] = ((size_t)bh*HD + vr)*SEQ + (vcs>>1);
  }

#define STG(bf_, kv_, i_) \
    gll16(Kb + kbase[i_] + (size_t)(kv_)*HD, &sm.s.k[bf_][w*2048 + i_*512]); \
    gll16(Vt + vbase[i_] + (kv_),            &sm.s.v[bf_][w*2048 + i_*512]);
#define STAGE(bf_, kv_) do { STG(bf_,kv_,0) STG(bf_,kv_,1) STG(bf_,kv_,2) STG(bf_,kv_,3) } while(0)

  fx4 accO[2][8] = {};              // O^T: row d = nn*16+g*4+r, col q
  float mrun[2] = {-1e30f,-1e30f}, lrun[2] = {0.f,0.f};

  STAGE(0, 0);
  __syncthreads();
  int buf = 0;

  for (int t=0; t<32; ++t){
    if (t < 31) STAGE(buf^1, (t+1)*64);
    const u16* sk = sm.s.k[buf];
    const u16* sv = sm.s.v[buf];

    // S^T = K @ Q^T : 64 kk-rows x 2x16 q-cols; each kf feeds both q-blocks
    fx4 st[2][4] = {};
    #pragma unroll
    for (int ks=0; ks<4; ++ks){
      bfx8 kf[4];
      #pragma unroll
      for (int n=0;n<4;n++){
        int row = n*16 + qi;
        int cb = ks*64 + g*16;
        kf[n] = *(const bfx8*)((const char*)sk + row*256 + (cb ^ ((row&7)<<4)));
      }
      #pragma unroll
      for (int n=0;n<4;n++){
        st[0][n] = MFMA_BF16(kf[n], qf[0][ks], st[0][n]);
        st[1][n] = MFMA_BF16(kf[n], qf[1][ks], st[1][n]);
      }
    }

    // online softmax (log2 domain); lane owns q, holds kk = n*16+g*4+r
    float pmv[2];
    #pragma unroll
    for (int j=0;j<2;j++){
      float pm = st[j][0][0];
      #pragma unroll
      for (int n=0;n<4;n++)
        #pragma unroll
        for (int r=0;r<4;r++) pm = fmaxf(pm, st[j][n][r]);
      pm = fmaxf(pm, __shfl_xor(pm, 16, 64));
      pm = fmaxf(pm, __shfl_xor(pm, 32, 64));
      pmv[j] = pm;
    }
    if (!__all((pmv[0] <= mrun[0] + 11.0f) && (pmv[1] <= mrun[1] + 11.0f))){   // T13 defer-max
      #pragma unroll
      for (int j=0;j<2;j++){
        float mn = fmaxf(mrun[j], pmv[j]);
        float al = exp2f(mrun[j] - mn);
        lrun[j] *= al;
        #pragma unroll
        for (int nn=0;nn<8;nn++) accO[j][nn] = accO[j][nn]*al;
        mrun[j] = mn;
      }
    }
    #pragma unroll
    for (int j=0;j<2;j++){
      float ps = 0.f;
      #pragma unroll
      for (int n=0;n<4;n++)
        #pragma unroll
        for (int r=0;r<4;r++){
          float p = exp2f(st[j][n][r] - mrun[j]);
          st[j][n][r] = p;
          ps += p;
        }
      ps += __shfl_xor(ps, 16, 64);
      ps += __shfl_xor(ps, 32, 64);
      lrun[j] += ps;
    }

    // pack P to bf16 pairs; lane (g',qi) reg pk[j][n]{l,h} = P_j[qi][n*16+g'*4+{0,1|2,3}]
    int pkl[2][4], pkh[2][4];
    #pragma unroll
    for (int j=0;j<2;j++)
      #pragma unroll
      for (int n=0;n<4;n++){
        pkl[j][n] = (int)cvtpk(st[j][n][0], st[j][n][1]);
        pkh[j][n] = (int)cvtpk(st[j][n][2], st[j][n][3]);
      }

    const int s0 = qi + 16*((2*g)&3);
    const int s1 = qi + 16*((2*g+1)&3);
    const bool hi = (g>>1) != 0;   // DEST-side register select

    // O^T += V^T @ P^T; vf read once feeds both q-blocks
    #pragma unroll
    for (int ks=0; ks<2; ++ks){
      bfx8 pv[2];
      #pragma unroll
      for (int j=0;j<2;j++){
        int cl0 = pkl[j][2*ks],   ch0 = pkh[j][2*ks];
        int cl1 = pkl[j][2*ks+1], ch1 = pkh[j][2*ks+1];
        int t00 = __shfl(cl0, s0, 64), t10 = __shfl(cl1, s0, 64);
        int t01 = __shfl(ch0, s0, 64), t11 = __shfl(ch1, s0, 64);
        int t02 = __shfl(cl0, s1, 64), t12 = __shfl(cl1, s1, 64);
        int t03 = __shfl(ch0, s1, 64), t13 = __shfl(ch1, s1, 64);
        union { bfx8 v; int u[4]; } pu;
        pu.u[0] = hi ? t10 : t00;
        pu.u[1] = hi ? t11 : t01;
        pu.u[2] = hi ? t12 : t02;
        pu.u[3] = hi ? t13 : t03;
        pv[j] = pu.v;
      }
      #pragma unroll
      for (int nn=0;nn<8;nn++){
        int row = nn*16 + qi;
        int cb = ks*64 + g*16;
        bfx8 vf = *(const bfx8*)((const char*)sv + row*128 + (cb ^ ((row&7)<<4)));
        accO[0][nn] = MFMA_BF16(vf, pv[0], accO[0][nn]);
        accO[1][nn] = MFMA_BF16(vf, pv[1], accO[1][nn]);
      }
    }
    __syncthreads();    // drains next-tile loads + guards buf reuse
    buf ^= 1;
  }
#undef STAGE
#undef STG

  // epilogue: O^T regs -> LDS (swizzled, 64KB) -> coalesced global
  #pragma unroll
  for (int j=0;j<2;j++){
    float inv = 1.0f / lrun[j];
    int q = w*32 + j*16 + qi;
    #pragma unroll
    for (int nn=0;nn<8;nn++)
      #pragma unroll
      for (int r=0;r<4;r++){
        int d = nn*16 + g*4 + r;
        *(float*)((char*)sm.ob + q*512 + ((d*4) ^ ((q&7)<<4))) = accO[j][nn][r]*inv;
      }
  }
  __syncthreads();
  {
    int q2 = tid>>1, c0 = (tid&1)*64;
    float* dst = O + ((size_t)(b*SEQ + qb0 + q2))*DM + h*HD + c0;
    #pragma unroll
    for (int jj=0;jj<16;jj++){
      int d0 = c0 + jj*4;
      float4 v = *(const float4*)((const char*)sm.ob + q2*512 + ((d0*4) ^ ((q2&7)<<4)));
      *(float4*)(dst + jj*4) = v;
    }
  }
}

// ----------------------------------------------------------------
extern "C" void kernel_launch(void* const* d_in, const int* in_sizes, int n_in,
                              void* d_out, int out_size, void* d_ws, size_t ws_size,
                              hipStream_t stream){
  (void)in_sizes; (void)n_in; (void)out_size; (void)ws_size;
  const float* x  = (const float*)d_in[0];
  const float* cs = (const float*)d_in[1];
  const float* sn = (const float*)d_in[2];
  const float* Wq = (const float*)d_in[3];
  const float* bq = (const float*)d_in[4];
  const float* Wk = (const float*)d_in[5];
  const float* bk = (const float*)d_in[6];
  const float* Wv = (const float*)d_in[7];
  const float* bv = (const float*)d_in[8];
  const float* Wo = (const float*)d_in[9];
  const float* bo = (const float*)d_in[10];
  float* out = (float*)d_out;

  char* ws = (char*)d_ws;
  const size_t MB = 1048576;
  u16* xb   = (u16*)(ws);              // 16 MB
  u16* wt   = (u16*)(ws + 16*MB);      //  8 MB
  u16* qb   = (u16*)(ws + 24*MB);      // 16 MB
  u16* kb   = (u16*)(ws + 40*MB);      // 16 MB
  u16* vt   = (u16*)(ws + 56*MB);      // 16 MB
  u16* ob16 = (u16*)(ws + 72*MB);      // 16 MB
  float* tmp = (float*)(ws + 88*MB);   // 32 MB; total 120 MB

  // scale^2 = 1/HD and log2(e) folded into q (rope is linear)
  const float rope_qscale = 1.4426950408889634f/128.0f;

  k_cast<<<8192,256,0,stream>>>(x, xb, 2097152);

  // Q
  k_tw<<<dim3(32,32),256,0,stream>>>(Wq, wt);
  k_gemm<<<dim3(16,32),256,0,stream>>>(xb, wt, bq, tmp, MR, DM, DM);
  k_rope<<<8192,256,0,stream>>>(tmp, cs, sn, qb, rope_qscale);
  // K
  k_tw<<<dim3(32,32),256,0,stream>>>(Wk, wt);
  k_gemm<<<dim3(16,32),256,0,stream>>>(xb, wt, bk, tmp, MR, DM, DM);
  k_rope<<<8192,256,0,stream>>>(tmp, cs, sn, kb, 1.0f);
  // V
  k_tw<<<dim3(32,32),256,0,stream>>>(Wv, wt);
  k_gemm<<<dim3(16,32),256,0,stream>>>(xb, wt, bv, tmp, MR, DM, DM);
  k_vt<<<1024,256,0,stream>>>(tmp, vt);

  // attention -> tmp (B,N,D) fp32
  k_flash<<<512,256,0,stream>>>(qb, kb, vt, tmp);

  // output projection
  k_cast<<<8192,256,0,stream>>>(tmp, ob16, 2097152);
  k_tw<<<dim3(32,32),256,0,stream>>>(Wo, wt);
  k_gemm<<<dim3(16,32),256,0,stream>>>(ob16, wt, bo, out, MR, DM, DM);
}

// Round 5
// 355.841 us; speedup vs baseline: 2.1401x; 1.1234x over previous
//
#include <hip/hip_runtime.h>

typedef unsigned short u16;
typedef __attribute__((ext_vector_type(8))) short bfx8;
typedef __attribute__((ext_vector_type(4))) float fx4;
typedef __attribute__((ext_vector_type(4))) unsigned short u16x4;

#define MFMA_BF16(a,b,c) __builtin_amdgcn_mfma_f32_16x16x32_bf16((a),(b),(c),0,0,0)

#define BATCH 2
#define SEQ   2048
#define DM    2048
#define NH    16
#define HD    128
#define MR    4096   /* BATCH*SEQ */

__device__ __forceinline__ u16 f2bf(float f){
  union{float f; unsigned u;} v; v.f = f;
  unsigned r = v.u + 0x7FFFu + ((v.u >> 16) & 1u);
  return (u16)(r >> 16);
}
__device__ __forceinline__ unsigned cvtpk(float lo, float hi){
  unsigned r;
  asm("v_cvt_pk_bf16_f32 %0, %1, %2" : "=v"(r) : "v"(lo), "v"(hi));
  return r;
}
__device__ __forceinline__ void gll16(const void* g, void* l){
  __builtin_amdgcn_global_load_lds(
      (const __attribute__((address_space(1))) void*)g,
      (__attribute__((address_space(3))) void*)l, 16, 0, 0);
}

// ---------------------------------------------------------------- fp32 -> bf16 cast (vectorized)
__global__ __launch_bounds__(256) void k_cast(const float* __restrict__ in,
                                              u16* __restrict__ o, int n4){
  int gid = blockIdx.x*256 + threadIdx.x;
  if (gid >= n4) return;
  float4 x = ((const float4*)in)[gid];
  u16x4 v = {f2bf(x.x), f2bf(x.y), f2bf(x.z), f2bf(x.w)};
  ((u16x4*)o)[gid] = v;
}

// ---------------------------------------------------------------- Wq/Wk/Wv [K][N] -> wt[6144][K] bf16 (concat transpose)
__global__ __launch_bounds__(256) void k_twcat(const float* __restrict__ Wq,
                                               const float* __restrict__ Wk,
                                               const float* __restrict__ Wv,
                                               u16* __restrict__ Th){
  __shared__ float T[64][65];
  int z = blockIdx.z;
  const float* W = (z==0) ? Wq : (z==1) ? Wk : Wv;
  int n0 = blockIdx.x*64, k0 = blockIdx.y*64;
  int t = threadIdx.x;
  int r = t>>2, c = (t&3)*16;
  const float* src = W + (size_t)(k0+r)*DM + n0 + c;
  #pragma unroll
  for (int j=0;j<4;j++){
    float4 v = *(const float4*)(src + 4*j);
    T[r][c+4*j+0]=v.x; T[r][c+4*j+1]=v.y; T[r][c+4*j+2]=v.z; T[r][c+4*j+3]=v.w;
  }
  __syncthreads();
  int nr = t>>2, kc = (t&3)*16;
  size_t ob = (size_t)(z*DM + n0+nr)*DM + k0 + kc;
  #pragma unroll
  for (int j=0;j<16;j+=4){
    u16x4 vh;
    #pragma unroll
    for (int q=0;q<4;q++) vh[q] = f2bf(T[kc+j+q][nr]);
    *(u16x4*)(Th+ob+j)=vh;
  }
}

// ---------------------------------------------------------------- Wo[K][N] -> wt[N][K] bf16
__global__ __launch_bounds__(256) void k_tw(const float* __restrict__ W, u16* __restrict__ Th){
  __shared__ float T[64][65];
  int n0 = blockIdx.x*64, k0 = blockIdx.y*64;
  int t = threadIdx.x;
  int r = t>>2, c = (t&3)*16;
  const float* src = W + (size_t)(k0+r)*DM + n0 + c;
  #pragma unroll
  for (int j=0;j<4;j++){
    float4 v = *(const float4*)(src + 4*j);
    T[r][c+4*j+0]=v.x; T[r][c+4*j+1]=v.y; T[r][c+4*j+2]=v.z; T[r][c+4*j+3]=v.w;
  }
  __syncthreads();
  int nr = t>>2, kc = (t&3)*16;
  size_t ob = (size_t)(n0+nr)*DM + k0 + kc;
  #pragma unroll
  for (int j=0;j<16;j+=4){
    u16x4 vh;
    #pragma unroll
    for (int q=0;q<4;q++) vh[q] = f2bf(T[kc+j+q][nr]);
    *(u16x4*)(Th+ob+j)=vh;
  }
}

// ---------------------------------------------------------------- fused QKV GEMM: [x]@[Wq|Wk|Wv]^T + bias, epilogue rope/transpose
// A: [4096][2048] bf16, B: wt [6144][2048] bf16
// sec 0: rope(scale*(.)) -> qb (B,H,N,HD) bf16 ; sec 1: rope -> kb ; sec 2: transpose -> vt (B,H,HD,N) bf16
__global__ __launch_bounds__(256) void k_gemm_qkv(
    const u16* __restrict__ A, const u16* __restrict__ B,
    const float* __restrict__ bqp, const float* __restrict__ bkp, const float* __restrict__ bvp,
    const float* __restrict__ cs, const float* __restrict__ sn,
    u16* __restrict__ qb, u16* __restrict__ kb, u16* __restrict__ vt)
{
  __shared__ u16 sA[128*64], sB[128*64];
  const int K = DM;
  const int tid = threadIdx.x;
  const int lane = tid & 63;
  const int w = tid >> 6;
  const int g = lane >> 4, qi = lane & 15;
  const int wr = w >> 1, wc = w & 1;
  const int bm = blockIdx.y * 128;
  const int bn = blockIdx.x * 128;

  int r_[4], sc_[4];
  #pragma unroll
  for (int i=0;i<4;i++){
    int off = w*4096 + i*1024 + lane*16;
    int r = off>>7, cb = off&127;
    r_[i] = r; sc_[i] = (cb ^ ((r&7)<<4)) >> 1;
  }

  fx4 acc[4][4] = {};

  for (int k0 = 0; k0 < K; k0 += 64){
    __syncthreads();
    #pragma unroll
    for (int i=0;i<4;i++){
      gll16(A + (size_t)(bm + r_[i])*K + k0 + sc_[i], &sA[w*2048 + i*512]);
      gll16(B + (size_t)(bn + r_[i])*K + k0 + sc_[i], &sB[w*2048 + i*512]);
    }
    __syncthreads();

    #pragma unroll
    for (int kk=0;kk<2;kk++){
      const int cb = kk*64 + g*16;
      bfx8 fa[4], fb[4];
      #pragma unroll
      for (int m=0;m<4;m++){
        int row = wr*64 + m*16 + qi;
        fa[m] = *(const bfx8*)((const char*)sA + row*128 + (cb ^ ((row&7)<<4)));
      }
      #pragma unroll
      for (int n=0;n<4;n++){
        int row = wc*64 + n*16 + qi;
        fb[n] = *(const bfx8*)((const char*)sB + row*128 + (cb ^ ((row&7)<<4)));
      }
      #pragma unroll
      for (int m=0;m<4;m++)
        #pragma unroll
        for (int n=0;n<4;n++)
          acc[m][n] = MFMA_BF16(fa[m], fb[n], acc[m][n]);
    }
  }

  const int sec = bn >> 11;   // 0=Q, 1=K, 2=V (block-uniform)
  if (sec < 2){
    u16* dst = sec ? kb : qb;
    const float* bias = sec ? bkp : bqp;
    const float qs = sec ? 1.0f : (1.4426950408889634f/128.0f);  // log2(e)*scale^2 folded into q
    #pragma unroll
    for (int m=0;m<4;m++){
      #pragma unroll
      for (int n=0;n<4;n++){
        int col = bn + wc*64 + n*16 + qi;
        int cq = col & 2047, hh = cq>>7, d = cq&127;
        float bc = bias[cq];
        float sgn = (d&1) ? 1.0f : -1.0f;
        #pragma unroll
        for (int r=0;r<4;r++){
          int row = bm + wr*64 + m*16 + g*4 + r;
          int bI = row>>11, nr2 = row&2047;
          float v = (acc[m][n][r] + bc)*qs;
          float p = __shfl_xor(v, 1, 64);     // partner (d^1) value, same row
          float c = cs[nr2*HD + d], s = sn[nr2*HD + d];
          float y = v*c + sgn*p*s;            // even d: v*c - p*s ; odd: v*c + p*s
          dst[((size_t)(bI*NH+hh)*SEQ + nr2)*HD + d] = f2bf(y);
        }
      }
    }
  } else {
    #pragma unroll
    for (int m=0;m<4;m++){
      #pragma unroll
      for (int n=0;n<4;n++){
        int col = bn + wc*64 + n*16 + qi;
        int cv = col & 2047, hh = cv>>7, d = cv&127;
        float bc = bvp[cv];
        int row0 = bm + wr*64 + m*16 + g*4;
        int bI = row0>>11, n0_ = row0&2047;
        u16x4 pk;
        #pragma unroll
        for (int r=0;r<4;r++) pk[r] = f2bf(acc[m][n][r] + bc);
        *(u16x4*)(vt + ((size_t)(bI*NH+hh)*HD + d)*SEQ + n0_) = pk;
      }
    }
  }
}

// ---------------------------------------------------------------- GEMM: C = A@B^T + bias (bf16, BK=64), fp32 out
__global__ __launch_bounds__(256) void k_gemm(
    const u16* __restrict__ A, const u16* __restrict__ B,
    const float* __restrict__ bias, float* __restrict__ C,
    int M, int N, int K)
{
  __shared__ u16 sA[128*64], sB[128*64];
  const int tid = threadIdx.x;
  const int lane = tid & 63;
  const int w = tid >> 6;
  const int g = lane >> 4, qi = lane & 15;
  const int wr = w >> 1, wc = w & 1;
  const int bm = blockIdx.y * 128;
  const int bn = blockIdx.x * 128;

  int r_[4], sc_[4];
  #pragma unroll
  for (int i=0;i<4;i++){
    int off = w*4096 + i*1024 + lane*16;
    int r = off>>7, cb = off&127;
    r_[i] = r; sc_[i] = (cb ^ ((r&7)<<4)) >> 1;
  }

  fx4 acc[4][4] = {};

  for (int k0 = 0; k0 < K; k0 += 64){
    __syncthreads();
    #pragma unroll
    for (int i=0;i<4;i++){
      gll16(A + (size_t)(bm + r_[i])*K + k0 + sc_[i], &sA[w*2048 + i*512]);
      gll16(B + (size_t)(bn + r_[i])*K + k0 + sc_[i], &sB[w*2048 + i*512]);
    }
    __syncthreads();

    #pragma unroll
    for (int kk=0;kk<2;kk++){
      const int cb = kk*64 + g*16;
      bfx8 fa[4], fb[4];
      #pragma unroll
      for (int m=0;m<4;m++){
        int row = wr*64 + m*16 + qi;
        fa[m] = *(const bfx8*)((const char*)sA + row*128 + (cb ^ ((row&7)<<4)));
      }
      #pragma unroll
      for (int n=0;n<4;n++){
        int row = wc*64 + n*16 + qi;
        fb[n] = *(const bfx8*)((const char*)sB + row*128 + (cb ^ ((row&7)<<4)));
      }
      #pragma unroll
      for (int m=0;m<4;m++)
        #pragma unroll
        for (int n=0;n<4;n++)
          acc[m][n] = MFMA_BF16(fa[m], fb[n], acc[m][n]);
    }
  }

  #pragma unroll
  for (int m=0;m<4;m++){
    #pragma unroll
    for (int n=0;n<4;n++){
      int col = bn + wc*64 + n*16 + qi;
      float bc = bias[col];
      #pragma unroll
      for (int r=0;r<4;r++){
        int row = bm + wr*64 + m*16 + g*4 + r;
        C[(size_t)row*N + col] = acc[m][n][r] + bc;
      }
    }
  }
}

// ---------------------------------------------------------------- flash attention (swapped-operand, counted-vmcnt barriers)
// Q: (B,H,N,HD) bf16 pre-scaled by log2(e)/HD; K: (B,H,N,HD) bf16; Vt: (B,H,HD,N) bf16; O: (B,N,D) bf16
__global__ __launch_bounds__(256) void k_flash(const u16* __restrict__ Q, const u16* __restrict__ Kb,
                                               const u16* __restrict__ Vt, u16* __restrict__ O){
  __shared__ union SM {
    struct { u16 k[2][64*128]; u16 v[2][128*64]; } s;   // 32KB + 32KB
    u16 ob[128*128];                                    // 32KB epilogue buffer
  } sm;
  const int tid = threadIdx.x, lane = tid & 63, w = tid >> 6;
  const int bid = blockIdx.x;
  const int qt = bid & 15, h = (bid>>4)&15, b = bid>>8;
  const int bh = b*NH + h;
  const int qb0 = qt*128;
  const int g = lane >> 4, qi = lane & 15;

  // Q as B-fragment, two q-column-blocks per wave (q = qb0 + w*32 + j*16 + qi)
  bfx8 qf[2][4];
  #pragma unroll
  for (int j=0;j<2;j++){
    const u16* qp = Q + ((size_t)bh*SEQ + qb0 + w*32 + j*16 + qi)*HD + g*8;
    #pragma unroll
    for (int ks=0; ks<4; ++ks) qf[j][ks] = *(const bfx8*)(qp + ks*32);
  }

  // staging source offsets (pre-swizzled global source, linear LDS dest)
  size_t kbase[4], vbase[4];
  #pragma unroll
  for (int i=0;i<4;i++){
    int off = w*4096 + i*1024 + lane*16;
    int kr = off>>8, kc = off&255;
    int kcs = kc ^ ((kr&7)<<4);
    kbase[i] = ((size_t)bh*SEQ + kr)*HD + (kcs>>1);
    int vr = off>>7, vc = off&127;
    int vcs = vc ^ ((vr&7)<<4);
    vbase[i] = ((size_t)bh*HD + vr)*SEQ + (vcs>>1);
  }

#define STG(bf_, kv_, i_) \
    gll16(Kb + kbase[i_] + (size_t)(kv_)*HD, &sm.s.k[bf_][w*2048 + i_*512]); \
    gll16(Vt + vbase[i_] + (kv_),            &sm.s.v[bf_][w*2048 + i_*512]);
#define STAGE(bf_, kv_) do { STG(bf_,kv_,0) STG(bf_,kv_,1) STG(bf_,kv_,2) STG(bf_,kv_,3) } while(0)

  fx4 accO[2][8] = {};              // O^T: row d = nn*16+g*4+r, col q
  float mrun[2] = {-1e30f,-1e30f}, lrun[2] = {0.f,0.f};

  STAGE(0, 0);                      // 8 loads in flight
  int buf = 0;

  for (int t=0; t<32; ++t){
    if (t < 31){
      STAGE(buf^1, (t+1)*64);       // +8 loads (16 outstanding)
      asm volatile("s_waitcnt vmcnt(8)" ::: "memory");   // tile t's 8 done; t+1's stay in flight
    } else {
      asm volatile("s_waitcnt vmcnt(0)" ::: "memory");
    }
    __builtin_amdgcn_s_barrier();   // raw barrier: no implicit drain
    const u16* sk = sm.s.k[buf];
    const u16* sv = sm.s.v[buf];

    // S^T = K @ Q^T : 64 kk-rows x 2x16 q-cols; each kf feeds both q-blocks
    fx4 st[2][4] = {};
    __builtin_amdgcn_s_setprio(1);
    #pragma unroll
    for (int ks=0; ks<4; ++ks){
      bfx8 kf[4];
      #pragma unroll
      for (int n=0;n<4;n++){
        int row = n*16 + qi;
        int cb = ks*64 + g*16;
        kf[n] = *(const bfx8*)((const char*)sk + row*256 + (cb ^ ((row&7)<<4)));
      }
      #pragma unroll
      for (int n=0;n<4;n++){
        st[0][n] = MFMA_BF16(kf[n], qf[0][ks], st[0][n]);
        st[1][n] = MFMA_BF16(kf[n], qf[1][ks], st[1][n]);
      }
    }
    __builtin_amdgcn_s_setprio(0);

    // online softmax (log2 domain); lane owns q, holds kk = n*16+g*4+r
    float pmv[2];
    #pragma unroll
    for (int j=0;j<2;j++){
      float pm = st[j][0][0];
      #pragma unroll
      for (int n=0;n<4;n++)
        #pragma unroll
        for (int r=0;r<4;r++) pm = fmaxf(pm, st[j][n][r]);
      pm = fmaxf(pm, __shfl_xor(pm, 16, 64));
      pm = fmaxf(pm, __shfl_xor(pm, 32, 64));
      pmv[j] = pm;
    }
    if (!__all((pmv[0] <= mrun[0] + 11.0f) && (pmv[1] <= mrun[1] + 11.0f))){   // T13 defer-max
      #pragma unroll
      for (int j=0;j<2;j++){
        float mn = fmaxf(mrun[j], pmv[j]);
        float al = exp2f(mrun[j] - mn);
        lrun[j] *= al;
        #pragma unroll
        for (int nn=0;nn<8;nn++) accO[j][nn] = accO[j][nn]*al;
        mrun[j] = mn;
      }
    }
    #pragma unroll
    for (int j=0;j<2;j++){
      float ps = 0.f;
      #pragma unroll
      for (int n=0;n<4;n++)
        #pragma unroll
        for (int r=0;r<4;r++){
          float p = exp2f(st[j][n][r] - mrun[j]);
          st[j][n][r] = p;
          ps += p;
        }
      ps += __shfl_xor(ps, 16, 64);
      ps += __shfl_xor(ps, 32, 64);
      lrun[j] += ps;
    }

    // pack P to bf16 pairs; lane (g',qi) reg pk[j][n]{l,h} = P_j[qi][n*16+g'*4+{0,1|2,3}]
    int pkl[2][4], pkh[2][4];
    #pragma unroll
    for (int j=0;j<2;j++)
      #pragma unroll
      for (int n=0;n<4;n++){
        pkl[j][n] = (int)cvtpk(st[j][n][0], st[j][n][1]);
        pkh[j][n] = (int)cvtpk(st[j][n][2], st[j][n][3]);
      }

    const int s0 = qi + 16*((2*g)&3);
    const int s1 = qi + 16*((2*g+1)&3);
    const bool hi = (g>>1) != 0;   // DEST-side register select

    // O^T += V^T @ P^T; vf read once feeds both q-blocks
    #pragma unroll
    for (int ks=0; ks<2; ++ks){
      bfx8 pv[2];
      #pragma unroll
      for (int j=0;j<2;j++){
        int cl0 = pkl[j][2*ks],   ch0 = pkh[j][2*ks];
        int cl1 = pkl[j][2*ks+1], ch1 = pkh[j][2*ks+1];
        int t00 = __shfl(cl0, s0, 64), t10 = __shfl(cl1, s0, 64);
        int t01 = __shfl(ch0, s0, 64), t11 = __shfl(ch1, s0, 64);
        int t02 = __shfl(cl0, s1, 64), t12 = __shfl(cl1, s1, 64);
        int t03 = __shfl(ch0, s1, 64), t13 = __shfl(ch1, s1, 64);
        union { bfx8 v; int u[4]; } pu;
        pu.u[0] = hi ? t10 : t00;
        pu.u[1] = hi ? t11 : t01;
        pu.u[2] = hi ? t12 : t02;
        pu.u[3] = hi ? t13 : t03;
        pv[j] = pu.v;
      }
      __builtin_amdgcn_s_setprio(1);
      #pragma unroll
      for (int nn=0;nn<8;nn++){
        int row = nn*16 + qi;
        int cb = ks*64 + g*16;
        bfx8 vf = *(const bfx8*)((const char*)sv + row*128 + (cb ^ ((row&7)<<4)));
        accO[0][nn] = MFMA_BF16(vf, pv[0], accO[0][nn]);
        accO[1][nn] = MFMA_BF16(vf, pv[1], accO[1][nn]);
      }
      __builtin_amdgcn_s_setprio(0);
    }
    __builtin_amdgcn_s_barrier();   // all waves done with buf before next STAGE overwrites its pair
    buf ^= 1;
  }
#undef STAGE
#undef STG

  // epilogue: O^T regs -> LDS u16 (swizzled) -> coalesced bf16 global
  #pragma unroll
  for (int j=0;j<2;j++){
    float inv = 1.0f / lrun[j];
    int q = w*32 + j*16 + qi;
    #pragma unroll
    for (int nn=0;nn<8;nn++)
      #pragma unroll
      for (int r=0;r<4;r++){
        int d = nn*16 + g*4 + r;
        *(u16*)((char*)sm.ob + q*256 + ((d*2) ^ ((q&7)<<4))) = f2bf(accO[j][nn][r]*inv);
      }
  }
  __syncthreads();
  {
    int q2 = tid>>1, c0 = (tid&1)*64;
    u16* dst = O + (size_t)(b*SEQ + qb0 + q2)*DM + h*HD + c0;
    #pragma unroll
    for (int jj=0;jj<8;jj++){
      int d0 = c0 + jj*8;
      bfx8 v = *(const bfx8*)((const char*)sm.ob + q2*256 + ((d0*2) ^ ((q2&7)<<4)));
      *(bfx8*)(dst + jj*8) = v;
    }
  }
}

// ----------------------------------------------------------------
extern "C" void kernel_launch(void* const* d_in, const int* in_sizes, int n_in,
                              void* d_out, int out_size, void* d_ws, size_t ws_size,
                              hipStream_t stream){
  (void)in_sizes; (void)n_in; (void)out_size; (void)ws_size;
  const float* x  = (const float*)d_in[0];
  const float* cs = (const float*)d_in[1];
  const float* sn = (const float*)d_in[2];
  const float* Wq = (const float*)d_in[3];
  const float* bq = (const float*)d_in[4];
  const float* Wk = (const float*)d_in[5];
  const float* bk = (const float*)d_in[6];
  const float* Wv = (const float*)d_in[7];
  const float* bv = (const float*)d_in[8];
  const float* Wo = (const float*)d_in[9];
  const float* bo = (const float*)d_in[10];
  float* out = (float*)d_out;

  char* ws = (char*)d_ws;
  const size_t MB = 1048576;
  u16* xb   = (u16*)(ws);              // 16 MB
  u16* wt   = (u16*)(ws + 16*MB);      // 24 MB (6144x2048 bf16; Wo reuses first 8MB)
  u16* qb   = (u16*)(ws + 40*MB);      // 16 MB
  u16* kb   = (u16*)(ws + 56*MB);      // 16 MB
  u16* vt   = (u16*)(ws + 72*MB);      // 16 MB
  u16* ob16 = (u16*)(ws + 88*MB);      // 16 MB; total 104 MB

  k_cast<<<8192,256,0,stream>>>(x, xb, 2097152);
  k_twcat<<<dim3(32,32,3),256,0,stream>>>(Wq, Wk, Wv, wt);
  k_gemm_qkv<<<dim3(48,32),256,0,stream>>>(xb, wt, bq, bk, bv, cs, sn, qb, kb, vt);

  // attention -> ob16 (B,N,D) bf16
  k_flash<<<512,256,0,stream>>>(qb, kb, vt, ob16);

  // output projection
  k_tw<<<dim3(32,32),256,0,stream>>>(Wo, wt);
  k_gemm<<<dim3(16,32),256,0,stream>>>(ob16, wt, bo, out, MR, DM, DM);
}

// Round 6
// 343.396 us; speedup vs baseline: 2.2176x; 1.0362x over previous
//
#include <hip/hip_runtime.h>

typedef unsigned short u16;
typedef __attribute__((ext_vector_type(8))) short bfx8;
typedef __attribute__((ext_vector_type(4))) float fx4;
typedef __attribute__((ext_vector_type(4))) unsigned short u16x4;

#define MFMA_BF16(a,b,c) __builtin_amdgcn_mfma_f32_16x16x32_bf16((a),(b),(c),0,0,0)

#define BATCH 2
#define SEQ   2048
#define DM    2048
#define NH    16
#define HD    128
#define MR    4096   /* BATCH*SEQ */

__device__ __forceinline__ u16 f2bf(float f){
  union{float f; unsigned u;} v; v.f = f;
  unsigned r = v.u + 0x7FFFu + ((v.u >> 16) & 1u);
  return (u16)(r >> 16);
}
__device__ __forceinline__ unsigned cvtpk(float lo, float hi){
  unsigned r;
  asm("v_cvt_pk_bf16_f32 %0, %1, %2" : "=v"(r) : "v"(lo), "v"(hi));
  return r;
}
__device__ __forceinline__ void gll16(const void* g, void* l){
  __builtin_amdgcn_global_load_lds(
      (const __attribute__((address_space(1))) void*)g,
      (__attribute__((address_space(3))) void*)l, 16, 0, 0);
}

// ---------------------------------------------------------------- fp32 -> bf16 cast (vectorized)
__global__ __launch_bounds__(256) void k_cast(const float* __restrict__ in,
                                              u16* __restrict__ o, int n4){
  int gid = blockIdx.x*256 + threadIdx.x;
  if (gid >= n4) return;
  float4 x = ((const float4*)in)[gid];
  u16x4 v = {f2bf(x.x), f2bf(x.y), f2bf(x.z), f2bf(x.w)};
  ((u16x4*)o)[gid] = v;
}

// ---------------------------------------------------------------- Wq/Wk/Wv [K][N] -> wt[6144][K] bf16 (concat transpose)
__global__ __launch_bounds__(256) void k_twcat(const float* __restrict__ Wq,
                                               const float* __restrict__ Wk,
                                               const float* __restrict__ Wv,
                                               u16* __restrict__ Th){
  __shared__ float T[64][65];
  int z = blockIdx.z;
  const float* W = (z==0) ? Wq : (z==1) ? Wk : Wv;
  int n0 = blockIdx.x*64, k0 = blockIdx.y*64;
  int t = threadIdx.x;
  int r = t>>2, c = (t&3)*16;
  const float* src = W + (size_t)(k0+r)*DM + n0 + c;
  #pragma unroll
  for (int j=0;j<4;j++){
    float4 v = *(const float4*)(src + 4*j);
    T[r][c+4*j+0]=v.x; T[r][c+4*j+1]=v.y; T[r][c+4*j+2]=v.z; T[r][c+4*j+3]=v.w;
  }
  __syncthreads();
  int nr = t>>2, kc = (t&3)*16;
  size_t ob = (size_t)(z*DM + n0+nr)*DM + k0 + kc;
  #pragma unroll
  for (int j=0;j<16;j+=4){
    u16x4 vh;
    #pragma unroll
    for (int q=0;q<4;q++) vh[q] = f2bf(T[kc+j+q][nr]);
    *(u16x4*)(Th+ob+j)=vh;
  }
}

// ---------------------------------------------------------------- Wo[K][N] -> wt[N][K] bf16
__global__ __launch_bounds__(256) void k_tw(const float* __restrict__ W, u16* __restrict__ Th){
  __shared__ float T[64][65];
  int n0 = blockIdx.x*64, k0 = blockIdx.y*64;
  int t = threadIdx.x;
  int r = t>>2, c = (t&3)*16;
  const float* src = W + (size_t)(k0+r)*DM + n0 + c;
  #pragma unroll
  for (int j=0;j<4;j++){
    float4 v = *(const float4*)(src + 4*j);
    T[r][c+4*j+0]=v.x; T[r][c+4*j+1]=v.y; T[r][c+4*j+2]=v.z; T[r][c+4*j+3]=v.w;
  }
  __syncthreads();
  int nr = t>>2, kc = (t&3)*16;
  size_t ob = (size_t)(n0+nr)*DM + k0 + kc;
  #pragma unroll
  for (int j=0;j<16;j+=4){
    u16x4 vh;
    #pragma unroll
    for (int q=0;q<4;q++) vh[q] = f2bf(T[kc+j+q][nr]);
    *(u16x4*)(Th+ob+j)=vh;
  }
}

// ---------------------------------------------------------------- fused QKV GEMM: [x]@[Wq|Wk|Wv]^T + bias, epilogue rope/transpose
__global__ __launch_bounds__(256) void k_gemm_qkv(
    const u16* __restrict__ A, const u16* __restrict__ B,
    const float* __restrict__ bqp, const float* __restrict__ bkp, const float* __restrict__ bvp,
    const float* __restrict__ cs, const float* __restrict__ sn,
    u16* __restrict__ qb, u16* __restrict__ kb, u16* __restrict__ vt)
{
  __shared__ u16 sA[128*64], sB[128*64];
  const int K = DM;
  const int tid = threadIdx.x;
  const int lane = tid & 63;
  const int w = tid >> 6;
  const int g = lane >> 4, qi = lane & 15;
  const int wr = w >> 1, wc = w & 1;
  const int bm = blockIdx.y * 128;
  const int bn = blockIdx.x * 128;

  int r_[4], sc_[4];
  #pragma unroll
  for (int i=0;i<4;i++){
    int off = w*4096 + i*1024 + lane*16;
    int r = off>>7, cb = off&127;
    r_[i] = r; sc_[i] = (cb ^ ((r&7)<<4)) >> 1;
  }

  fx4 acc[4][4] = {};

  for (int k0 = 0; k0 < K; k0 += 64){
    __syncthreads();
    #pragma unroll
    for (int i=0;i<4;i++){
      gll16(A + (size_t)(bm + r_[i])*K + k0 + sc_[i], &sA[w*2048 + i*512]);
      gll16(B + (size_t)(bn + r_[i])*K + k0 + sc_[i], &sB[w*2048 + i*512]);
    }
    __syncthreads();

    #pragma unroll
    for (int kk=0;kk<2;kk++){
      const int cb = kk*64 + g*16;
      bfx8 fa[4], fb[4];
      #pragma unroll
      for (int m=0;m<4;m++){
        int row = wr*64 + m*16 + qi;
        fa[m] = *(const bfx8*)((const char*)sA + row*128 + (cb ^ ((row&7)<<4)));
      }
      #pragma unroll
      for (int n=0;n<4;n++){
        int row = wc*64 + n*16 + qi;
        fb[n] = *(const bfx8*)((const char*)sB + row*128 + (cb ^ ((row&7)<<4)));
      }
      #pragma unroll
      for (int m=0;m<4;m++)
        #pragma unroll
        for (int n=0;n<4;n++)
          acc[m][n] = MFMA_BF16(fa[m], fb[n], acc[m][n]);
    }
  }

  const int sec = bn >> 11;   // 0=Q, 1=K, 2=V (block-uniform)
  if (sec < 2){
    u16* dst = sec ? kb : qb;
    const float* bias = sec ? bkp : bqp;
    const float qs = sec ? 1.0f : (1.4426950408889634f/128.0f);  // log2(e)*scale^2 folded into q
    #pragma unroll
    for (int m=0;m<4;m++){
      #pragma unroll
      for (int n=0;n<4;n++){
        int col = bn + wc*64 + n*16 + qi;
        int cq = col & 2047, hh = cq>>7, d = cq&127;
        float bc = bias[cq];
        float sgn = (d&1) ? 1.0f : -1.0f;
        #pragma unroll
        for (int r=0;r<4;r++){
          int row = bm + wr*64 + m*16 + g*4 + r;
          int bI = row>>11, nr2 = row&2047;
          float v = (acc[m][n][r] + bc)*qs;
          float p = __shfl_xor(v, 1, 64);     // partner (d^1) value, same row
          float c = cs[nr2*HD + d], s = sn[nr2*HD + d];
          float y = v*c + sgn*p*s;            // even d: v*c - p*s ; odd: v*c + p*s
          dst[((size_t)(bI*NH+hh)*SEQ + nr2)*HD + d] = f2bf(y);
        }
      }
    }
  } else {
    #pragma unroll
    for (int m=0;m<4;m++){
      #pragma unroll
      for (int n=0;n<4;n++){
        int col = bn + wc*64 + n*16 + qi;
        int cv = col & 2047, hh = cv>>7, d = cv&127;
        float bc = bvp[cv];
        int row0 = bm + wr*64 + m*16 + g*4;
        int bI = row0>>11, n0_ = row0&2047;
        u16x4 pk;
        #pragma unroll
        for (int r=0;r<4;r++) pk[r] = f2bf(acc[m][n][r] + bc);
        *(u16x4*)(vt + ((size_t)(bI*NH+hh)*HD + d)*SEQ + n0_) = pk;
      }
    }
  }
}

// ---------------------------------------------------------------- GEMM: C = A@B^T + bias (bf16, BK=64), fp32 out
__global__ __launch_bounds__(256) void k_gemm(
    const u16* __restrict__ A, const u16* __restrict__ B,
    const float* __restrict__ bias, float* __restrict__ C,
    int M, int N, int K)
{
  __shared__ u16 sA[128*64], sB[128*64];
  const int tid = threadIdx.x;
  const int lane = tid & 63;
  const int w = tid >> 6;
  const int g = lane >> 4, qi = lane & 15;
  const int wr = w >> 1, wc = w & 1;
  const int bm = blockIdx.y * 128;
  const int bn = blockIdx.x * 128;

  int r_[4], sc_[4];
  #pragma unroll
  for (int i=0;i<4;i++){
    int off = w*4096 + i*1024 + lane*16;
    int r = off>>7, cb = off&127;
    r_[i] = r; sc_[i] = (cb ^ ((r&7)<<4)) >> 1;
  }

  fx4 acc[4][4] = {};

  for (int k0 = 0; k0 < K; k0 += 64){
    __syncthreads();
    #pragma unroll
    for (int i=0;i<4;i++){
      gll16(A + (size_t)(bm + r_[i])*K + k0 + sc_[i], &sA[w*2048 + i*512]);
      gll16(B + (size_t)(bn + r_[i])*K + k0 + sc_[i], &sB[w*2048 + i*512]);
    }
    __syncthreads();

    #pragma unroll
    for (int kk=0;kk<2;kk++){
      const int cb = kk*64 + g*16;
      bfx8 fa[4], fb[4];
      #pragma unroll
      for (int m=0;m<4;m++){
        int row = wr*64 + m*16 + qi;
        fa[m] = *(const bfx8*)((const char*)sA + row*128 + (cb ^ ((row&7)<<4)));
      }
      #pragma unroll
      for (int n=0;n<4;n++){
        int row = wc*64 + n*16 + qi;
        fb[n] = *(const bfx8*)((const char*)sB + row*128 + (cb ^ ((row&7)<<4)));
      }
      #pragma unroll
      for (int m=0;m<4;m++)
        #pragma unroll
        for (int n=0;n<4;n++)
          acc[m][n] = MFMA_BF16(fa[m], fb[n], acc[m][n]);
    }
  }

  #pragma unroll
  for (int m=0;m<4;m++){
    #pragma unroll
    for (int n=0;n<4;n++){
      int col = bn + wc*64 + n*16 + qi;
      float bc = bias[col];
      #pragma unroll
      for (int r=0;r<4;r++){
        int row = bm + wr*64 + m*16 + g*4 + r;
        C[(size_t)row*N + col] = acc[m][n][r] + bc;
      }
    }
  }
}

// ---------------------------------------------------------------- flash attention v3: 2-wave blocks, single-buffered K/V,
// 4-barrier counted-vmcnt schedule (each load phase hides under a compute phase).
// Q: (B,H,N,HD) bf16 pre-scaled by log2(e)/HD; K: (B,H,N,HD) bf16; Vt: (B,H,HD,N) bf16; O: (B,N,D) bf16
__global__ __launch_bounds__(128) void k_flash(const u16* __restrict__ Q, const u16* __restrict__ Kb,
                                               const u16* __restrict__ Vt, u16* __restrict__ O){
  __shared__ union SM {
    struct { u16 k[64*128]; u16 v[128*64]; } s;   // 16KB + 16KB
    u16 ob[64*128];                               // 16KB epilogue buffer
  } sm;
  const int tid = threadIdx.x, lane = tid & 63, w = tid >> 6;   // w in {0,1}
  const int bid = blockIdx.x;
  const int qt = bid & 31, h = (bid>>5)&15, b = bid>>9;
  const int bh = b*NH + h;
  const int qb0 = qt*64;
  const int g = lane >> 4, qi = lane & 15;

  // Q as B-fragment, two q-column-blocks per wave (q = qb0 + w*32 + j*16 + qi)
  bfx8 qf[2][4];
  #pragma unroll
  for (int j=0;j<2;j++){
    const u16* qp = Q + ((size_t)bh*SEQ + qb0 + w*32 + j*16 + qi)*HD + g*8;
    #pragma unroll
    for (int ks=0; ks<4; ++ks) qf[j][ks] = *(const bfx8*)(qp + ks*32);
  }

  // staging source offsets (pre-swizzled global source, linear LDS dest); 8 loads/wave each for K and V
  size_t kbase[8], vbase[8];
  #pragma unroll
  for (int i=0;i<8;i++){
    int off = w*8192 + i*1024 + lane*16;
    int kr = off>>8, kc = off&255;
    int kcs = kc ^ ((kr&7)<<4);
    kbase[i] = ((size_t)bh*SEQ + kr)*HD + (kcs>>1);
    int vr = off>>7, vc = off&127;
    int vcs = vc ^ ((vr&7)<<4);
    vbase[i] = ((size_t)bh*HD + vr)*SEQ + (vcs>>1);
  }

#define STAGE_K(kv_) do { _Pragma("unroll") \
    for (int i_=0;i_<8;i_++) gll16(Kb + kbase[i_] + (size_t)(kv_)*HD, &sm.s.k[w*4096 + i_*512]); } while(0)
#define STAGE_V(kv_) do { _Pragma("unroll") \
    for (int i_=0;i_<8;i_++) gll16(Vt + vbase[i_] + (kv_),            &sm.s.v[w*4096 + i_*512]); } while(0)

  fx4 accO[2][8] = {};              // O^T: row d = nn*16+g*4+r, col q
  float mrun[2] = {-1e30f,-1e30f};
  float lrun[2] = {0.f,0.f};        // lane-local partial sum of p (reduced once at end)

  STAGE_K(0);                       // 8 loads (K(0))
  STAGE_V(0);                       // +8 loads (V(0))

  for (int t=0; t<32; ++t){
    // K(t) ready: outstanding = K(t)[8, oldest] + V(t)[8]; retire the 8 oldest
    asm volatile("s_waitcnt vmcnt(8)" ::: "memory");
    __builtin_amdgcn_s_barrier();                       // A: K(t) visible to both waves

    // S^T = K @ Q^T : 64 kk-rows x 2x16 q-cols
    fx4 st[2][4] = {};
    __builtin_amdgcn_s_setprio(1);
    #pragma unroll
    for (int ks=0; ks<4; ++ks){
      bfx8 kf[4];
      #pragma unroll
      for (int n=0;n<4;n++){
        int row = n*16 + qi;
        int cb = ks*64 + g*16;
        kf[n] = *(const bfx8*)((const char*)sm.s.k + row*256 + (cb ^ ((row&7)<<4)));
      }
      #pragma unroll
      for (int n=0;n<4;n++){
        st[0][n] = MFMA_BF16(kf[n], qf[0][ks], st[0][n]);
        st[1][n] = MFMA_BF16(kf[n], qf[1][ks], st[1][n]);
      }
    }
    __builtin_amdgcn_s_setprio(0);
    __builtin_amdgcn_s_barrier();                       // B: both waves done reading sK
    if (t < 31) STAGE_K(t*64 + 64);                     // K(t+1) lands during softmax+PV

    // online softmax (log2 domain); lane owns q, holds kk = n*16+g*4+r
    float pmv[2];
    #pragma unroll
    for (int j=0;j<2;j++){
      float pm = st[j][0][0];
      #pragma unroll
      for (int n=0;n<4;n++)
        #pragma unroll
        for (int r=0;r<4;r++) pm = fmaxf(pm, st[j][n][r]);
      pmv[j] = pm;                                      // lane-local max (no reduce in common path)
    }
    if (!__all((pmv[0] <= mrun[0] + 11.0f) && (pmv[1] <= mrun[1] + 11.0f))){   // T13 defer-max
      #pragma unroll
      for (int j=0;j<2;j++){
        float pq = pmv[j];
        pq = fmaxf(pq, __shfl_xor(pq, 16, 64));         // q-reduce only on rescale path
        pq = fmaxf(pq, __shfl_xor(pq, 32, 64));
        float mn = fmaxf(mrun[j], pq);
        float al = exp2f(mrun[j] - mn);
        lrun[j] *= al;
        #pragma unroll
        for (int nn=0;nn<8;nn++) accO[j][nn] = accO[j][nn]*al;
        mrun[j] = mn;
      }
    }
    #pragma unroll
    for (int j=0;j<2;j++){
      float ps = 0.f;
      #pragma unroll
      for (int n=0;n<4;n++)
        #pragma unroll
        for (int r=0;r<4;r++){
          float p = exp2f(st[j][n][r] - mrun[j]);
          st[j][n][r] = p;
          ps += p;
        }
      lrun[j] += ps;                                    // lane-local; no shuffle
    }

    // pack P to bf16 pairs; lane (g',qi) reg pk[j][n]{l,h} = P_j[qi][n*16+g'*4+{0,1|2,3}]
    int pkl[2][4], pkh[2][4];
    #pragma unroll
    for (int j=0;j<2;j++)
      #pragma unroll
      for (int n=0;n<4;n++){
        pkl[j][n] = (int)cvtpk(st[j][n][0], st[j][n][1]);
        pkh[j][n] = (int)cvtpk(st[j][n][2], st[j][n][3]);
      }

    // V(t) ready: outstanding = V(t)[8, oldest] + K(t+1)[8] (t<31) -> vmcnt(8); t==31 -> vmcnt(0)
    if (t < 31) asm volatile("s_waitcnt vmcnt(8)" ::: "memory");
    else        asm volatile("s_waitcnt vmcnt(0)" ::: "memory");
    __builtin_amdgcn_s_barrier();                       // C: V(t) visible

    const int s0 = qi + 16*((2*g)&3);
    const int s1 = qi + 16*((2*g+1)&3);
    const bool hi = (g>>1) != 0;   // DEST-side register select

    // O^T += V^T @ P^T
    #pragma unroll
    for (int ks=0; ks<2; ++ks){
      bfx8 pv[2];
      #pragma unroll
      for (int j=0;j<2;j++){
        int cl0 = pkl[j][2*ks],   ch0 = pkh[j][2*ks];
        int cl1 = pkl[j][2*ks+1], ch1 = pkh[j][2*ks+1];
        int t00 = __shfl(cl0, s0, 64), t10 = __shfl(cl1, s0, 64);
        int t01 = __shfl(ch0, s0, 64), t11 = __shfl(ch1, s0, 64);
        int t02 = __shfl(cl0, s1, 64), t12 = __shfl(cl1, s1, 64);
        int t03 = __shfl(ch0, s1, 64), t13 = __shfl(ch1, s1, 64);
        union { bfx8 v; int u[4]; } pu;
        pu.u[0] = hi ? t10 : t00;
        pu.u[1] = hi ? t11 : t01;
        pu.u[2] = hi ? t12 : t02;
        pu.u[3] = hi ? t13 : t03;
        pv[j] = pu.v;
      }
      __builtin_amdgcn_s_setprio(1);
      #pragma unroll
      for (int nn=0;nn<8;nn++){
        int row = nn*16 + qi;
        int cb = ks*64 + g*16;
        bfx8 vf = *(const bfx8*)((const char*)sm.s.v + row*128 + (cb ^ ((row&7)<<4)));
        accO[0][nn] = MFMA_BF16(vf, pv[0], accO[0][nn]);
        accO[1][nn] = MFMA_BF16(vf, pv[1], accO[1][nn]);
      }
      __builtin_amdgcn_s_setprio(0);
    }
    __builtin_amdgcn_s_barrier();                       // D: both waves done reading sV
    if (t < 31) STAGE_V(t*64 + 64);                     // V(t+1) lands during next QK^T+softmax
  }
#undef STAGE_K
#undef STAGE_V

  // epilogue: reduce l, O^T regs -> LDS u16 (swizzled) -> coalesced bf16 global
  #pragma unroll
  for (int j=0;j<2;j++){
    float l = lrun[j];
    l += __shfl_xor(l, 16, 64);
    l += __shfl_xor(l, 32, 64);
    float inv = 1.0f / l;
    int q = w*32 + j*16 + qi;
    #pragma unroll
    for (int nn=0;nn<8;nn++)
      #pragma unroll
      for (int r=0;r<4;r++){
        int d = nn*16 + g*4 + r;
        *(u16*)((char*)sm.ob + q*256 + ((d*2) ^ ((q&7)<<4))) = f2bf(accO[j][nn][r]*inv);
      }
  }
  __syncthreads();
  {
    int q2 = tid>>1, c0 = (tid&1)*64;
    u16* dst = O + (size_t)(b*SEQ + qb0 + q2)*DM + h*HD + c0;
    #pragma unroll
    for (int jj=0;jj<8;jj++){
      int d0 = c0 + jj*8;
      bfx8 v = *(const bfx8*)((const char*)sm.ob + q2*256 + ((d0*2) ^ ((q2&7)<<4)));
      *(bfx8*)(dst + jj*8) = v;
    }
  }
}

// ----------------------------------------------------------------
extern "C" void kernel_launch(void* const* d_in, const int* in_sizes, int n_in,
                              void* d_out, int out_size, void* d_ws, size_t ws_size,
                              hipStream_t stream){
  (void)in_sizes; (void)n_in; (void)out_size; (void)ws_size;
  const float* x  = (const float*)d_in[0];
  const float* cs = (const float*)d_in[1];
  const float* sn = (const float*)d_in[2];
  const float* Wq = (const float*)d_in[3];
  const float* bq = (const float*)d_in[4];
  const float* Wk = (const float*)d_in[5];
  const float* bk = (const float*)d_in[6];
  const float* Wv = (const float*)d_in[7];
  const float* bv = (const float*)d_in[8];
  const float* Wo = (const float*)d_in[9];
  const float* bo = (const float*)d_in[10];
  float* out = (float*)d_out;

  char* ws = (char*)d_ws;
  const size_t MB = 1048576;
  u16* xb   = (u16*)(ws);              // 16 MB
  u16* wt   = (u16*)(ws + 16*MB);      // 24 MB (6144x2048 bf16; Wo reuses first 8MB)
  u16* qb   = (u16*)(ws + 40*MB);      // 16 MB
  u16* kb   = (u16*)(ws + 56*MB);      // 16 MB
  u16* vt   = (u16*)(ws + 72*MB);      // 16 MB
  u16* ob16 = (u16*)(ws + 88*MB);      // 16 MB; total 104 MB

  k_cast<<<8192,256,0,stream>>>(x, xb, 2097152);
  k_twcat<<<dim3(32,32,3),256,0,stream>>>(Wq, Wk, Wv, wt);
  k_gemm_qkv<<<dim3(48,32),256,0,stream>>>(xb, wt, bq, bk, bv, cs, sn, qb, kb, vt);

  // attention -> ob16 (B,N,D) bf16
  k_flash<<<1024,128,0,stream>>>(qb, kb, vt, ob16);

  // output projection
  k_tw<<<dim3(32,32),256,0,stream>>>(Wo, wt);
  k_gemm<<<dim3(16,32),256,0,stream>>>(ob16, wt, bo, out, MR, DM, DM);
}

// Round 7
// 328.422 us; speedup vs baseline: 2.3187x; 1.0456x over previous
//
#include <hip/hip_runtime.h>

typedef unsigned short u16;
typedef unsigned int u32;
typedef __attribute__((ext_vector_type(8))) short bfx8;
typedef __attribute__((ext_vector_type(4))) float fx4;
typedef __attribute__((ext_vector_type(16))) float fx16;
typedef __attribute__((ext_vector_type(4))) unsigned short u16x4;

#define MFMA_BF16(a,b,c)   __builtin_amdgcn_mfma_f32_16x16x32_bf16((a),(b),(c),0,0,0)
#define MFMA32_BF16(a,b,c) __builtin_amdgcn_mfma_f32_32x32x16_bf16((a),(b),(c),0,0,0)

#define BATCH 2
#define SEQ   2048
#define DM    2048
#define NH    16
#define HD    128
#define MR    4096   /* BATCH*SEQ */

__device__ __forceinline__ u16 f2bf(float f){
  union{float f; unsigned u;} v; v.f = f;
  unsigned r = v.u + 0x7FFFu + ((v.u >> 16) & 1u);
  return (u16)(r >> 16);
}
__device__ __forceinline__ unsigned cvtpk(float lo, float hi){
  unsigned r;
  asm("v_cvt_pk_bf16_f32 %0, %1, %2" : "=v"(r) : "v"(lo), "v"(hi));
  return r;
}
__device__ __forceinline__ void gll16(const void* g, void* l){
  __builtin_amdgcn_global_load_lds(
      (const __attribute__((address_space(1))) void*)g,
      (__attribute__((address_space(3))) void*)l, 16, 0, 0);
}

// ---------------------------------------------------------------- fp32 -> bf16 cast (vectorized)
__global__ __launch_bounds__(256) void k_cast(const float* __restrict__ in,
                                              u16* __restrict__ o, int n4){
  int gid = blockIdx.x*256 + threadIdx.x;
  if (gid >= n4) return;
  float4 x = ((const float4*)in)[gid];
  u16x4 v = {f2bf(x.x), f2bf(x.y), f2bf(x.z), f2bf(x.w)};
  ((u16x4*)o)[gid] = v;
}

// ---------------------------------------------------------------- Wq/Wk/Wv [K][N] -> wt[6144][K] bf16 (concat transpose)
__global__ __launch_bounds__(256) void k_twcat(const float* __restrict__ Wq,
                                               const float* __restrict__ Wk,
                                               const float* __restrict__ Wv,
                                               u16* __restrict__ Th){
  __shared__ float T[64][65];
  int z = blockIdx.z;
  const float* W = (z==0) ? Wq : (z==1) ? Wk : Wv;
  int n0 = blockIdx.x*64, k0 = blockIdx.y*64;
  int t = threadIdx.x;
  int r = t>>2, c = (t&3)*16;
  const float* src = W + (size_t)(k0+r)*DM + n0 + c;
  #pragma unroll
  for (int j=0;j<4;j++){
    float4 v = *(const float4*)(src + 4*j);
    T[r][c+4*j+0]=v.x; T[r][c+4*j+1]=v.y; T[r][c+4*j+2]=v.z; T[r][c+4*j+3]=v.w;
  }
  __syncthreads();
  int nr = t>>2, kc = (t&3)*16;
  size_t ob = (size_t)(z*DM + n0+nr)*DM + k0 + kc;
  #pragma unroll
  for (int j=0;j<16;j+=4){
    u16x4 vh;
    #pragma unroll
    for (int q=0;q<4;q++) vh[q] = f2bf(T[kc+j+q][nr]);
    *(u16x4*)(Th+ob+j)=vh;
  }
}

// ---------------------------------------------------------------- Wo[K][N] -> wt[N][K] bf16
__global__ __launch_bounds__(256) void k_tw(const float* __restrict__ W, u16* __restrict__ Th){
  __shared__ float T[64][65];
  int n0 = blockIdx.x*64, k0 = blockIdx.y*64;
  int t = threadIdx.x;
  int r = t>>2, c = (t&3)*16;
  const float* src = W + (size_t)(k0+r)*DM + n0 + c;
  #pragma unroll
  for (int j=0;j<4;j++){
    float4 v = *(const float4*)(src + 4*j);
    T[r][c+4*j+0]=v.x; T[r][c+4*j+1]=v.y; T[r][c+4*j+2]=v.z; T[r][c+4*j+3]=v.w;
  }
  __syncthreads();
  int nr = t>>2, kc = (t&3)*16;
  size_t ob = (size_t)(n0+nr)*DM + k0 + kc;
  #pragma unroll
  for (int j=0;j<16;j+=4){
    u16x4 vh;
    #pragma unroll
    for (int q=0;q<4;q++) vh[q] = f2bf(T[kc+j+q][nr]);
    *(u16x4*)(Th+ob+j)=vh;
  }
}

// ---------------------------------------------------------------- fused QKV GEMM: [x]@[Wq|Wk|Wv]^T + bias, epilogue rope/transpose
__global__ __launch_bounds__(256) void k_gemm_qkv(
    const u16* __restrict__ A, const u16* __restrict__ B,
    const float* __restrict__ bqp, const float* __restrict__ bkp, const float* __restrict__ bvp,
    const float* __restrict__ cs, const float* __restrict__ sn,
    u16* __restrict__ qb, u16* __restrict__ kb, u16* __restrict__ vt)
{
  __shared__ u16 sA[128*64], sB[128*64];
  const int K = DM;
  const int tid = threadIdx.x;
  const int lane = tid & 63;
  const int w = tid >> 6;
  const int g = lane >> 4, qi = lane & 15;
  const int wr = w >> 1, wc = w & 1;
  const int bm = blockIdx.y * 128;
  const int bn = blockIdx.x * 128;

  int r_[4], sc_[4];
  #pragma unroll
  for (int i=0;i<4;i++){
    int off = w*4096 + i*1024 + lane*16;
    int r = off>>7, cb = off&127;
    r_[i] = r; sc_[i] = (cb ^ ((r&7)<<4)) >> 1;
  }

  fx4 acc[4][4] = {};

  for (int k0 = 0; k0 < K; k0 += 64){
    __syncthreads();
    #pragma unroll
    for (int i=0;i<4;i++){
      gll16(A + (size_t)(bm + r_[i])*K + k0 + sc_[i], &sA[w*2048 + i*512]);
      gll16(B + (size_t)(bn + r_[i])*K + k0 + sc_[i], &sB[w*2048 + i*512]);
    }
    __syncthreads();

    #pragma unroll
    for (int kk=0;kk<2;kk++){
      const int cb = kk*64 + g*16;
      bfx8 fa[4], fb[4];
      #pragma unroll
      for (int m=0;m<4;m++){
        int row = wr*64 + m*16 + qi;
        fa[m] = *(const bfx8*)((const char*)sA + row*128 + (cb ^ ((row&7)<<4)));
      }
      #pragma unroll
      for (int n=0;n<4;n++){
        int row = wc*64 + n*16 + qi;
        fb[n] = *(const bfx8*)((const char*)sB + row*128 + (cb ^ ((row&7)<<4)));
      }
      #pragma unroll
      for (int m=0;m<4;m++)
        #pragma unroll
        for (int n=0;n<4;n++)
          acc[m][n] = MFMA_BF16(fa[m], fb[n], acc[m][n]);
    }
  }

  const int sec = bn >> 11;   // 0=Q, 1=K, 2=V (block-uniform)
  if (sec < 2){
    u16* dst = sec ? kb : qb;
    const float* bias = sec ? bkp : bqp;
    const float qs = sec ? 1.0f : (1.4426950408889634f/128.0f);  // log2(e)*scale^2 folded into q
    #pragma unroll
    for (int m=0;m<4;m++){
      #pragma unroll
      for (int n=0;n<4;n++){
        int col = bn + wc*64 + n*16 + qi;
        int cq = col & 2047, hh = cq>>7, d = cq&127;
        float bc = bias[cq];
        float sgn = (d&1) ? 1.0f : -1.0f;
        #pragma unroll
        for (int r=0;r<4;r++){
          int row = bm + wr*64 + m*16 + g*4 + r;
          int bI = row>>11, nr2 = row&2047;
          float v = (acc[m][n][r] + bc)*qs;
          float p = __shfl_xor(v, 1, 64);     // partner (d^1) value, same row
          float c = cs[nr2*HD + d], s = sn[nr2*HD + d];
          float y = v*c + sgn*p*s;            // even d: v*c - p*s ; odd: v*c + p*s
          dst[((size_t)(bI*NH+hh)*SEQ + nr2)*HD + d] = f2bf(y);
        }
      }
    }
  } else {
    #pragma unroll
    for (int m=0;m<4;m++){
      #pragma unroll
      for (int n=0;n<4;n++){
        int col = bn + wc*64 + n*16 + qi;
        int cv = col & 2047, hh = cv>>7, d = cv&127;
        float bc = bvp[cv];
        int row0 = bm + wr*64 + m*16 + g*4;
        int bI = row0>>11, n0_ = row0&2047;
        u16x4 pk;
        #pragma unroll
        for (int r=0;r<4;r++) pk[r] = f2bf(acc[m][n][r] + bc);
        *(u16x4*)(vt + ((size_t)(bI*NH+hh)*HD + d)*SEQ + n0_) = pk;
      }
    }
  }
}

// ---------------------------------------------------------------- GEMM: C = A@B^T + bias (bf16, BK=64), fp32 out
__global__ __launch_bounds__(256) void k_gemm(
    const u16* __restrict__ A, const u16* __restrict__ B,
    const float* __restrict__ bias, float* __restrict__ C,
    int M, int N, int K)
{
  __shared__ u16 sA[128*64], sB[128*64];
  const int tid = threadIdx.x;
  const int lane = tid & 63;
  const int w = tid >> 6;
  const int g = lane >> 4, qi = lane & 15;
  const int wr = w >> 1, wc = w & 1;
  const int bm = blockIdx.y * 128;
  const int bn = blockIdx.x * 128;

  int r_[4], sc_[4];
  #pragma unroll
  for (int i=0;i<4;i++){
    int off = w*4096 + i*1024 + lane*16;
    int r = off>>7, cb = off&127;
    r_[i] = r; sc_[i] = (cb ^ ((r&7)<<4)) >> 1;
  }

  fx4 acc[4][4] = {};

  for (int k0 = 0; k0 < K; k0 += 64){
    __syncthreads();
    #pragma unroll
    for (int i=0;i<4;i++){
      gll16(A + (size_t)(bm + r_[i])*K + k0 + sc_[i], &sA[w*2048 + i*512]);
      gll16(B + (size_t)(bn + r_[i])*K + k0 + sc_[i], &sB[w*2048 + i*512]);
    }
    __syncthreads();

    #pragma unroll
    for (int kk=0;kk<2;kk++){
      const int cb = kk*64 + g*16;
      bfx8 fa[4], fb[4];
      #pragma unroll
      for (int m=0;m<4;m++){
        int row = wr*64 + m*16 + qi;
        fa[m] = *(const bfx8*)((const char*)sA + row*128 + (cb ^ ((row&7)<<4)));
      }
      #pragma unroll
      for (int n=0;n<4;n++){
        int row = wc*64 + n*16 + qi;
        fb[n] = *(const bfx8*)((const char*)sB + row*128 + (cb ^ ((row&7)<<4)));
      }
      #pragma unroll
      for (int m=0;m<4;m++)
        #pragma unroll
        for (int n=0;n<4;n++)
          acc[m][n] = MFMA_BF16(fa[m], fb[n], acc[m][n]);
    }
  }

  #pragma unroll
  for (int m=0;m<4;m++){
    #pragma unroll
    for (int n=0;n<4;n++){
      int col = bn + wc*64 + n*16 + qi;
      float bc = bias[col];
      #pragma unroll
      for (int r=0;r<4;r++){
        int row = bm + wr*64 + m*16 + g*4 + r;
        C[(size_t)row*N + col] = acc[m][n][r] + bc;
      }
    }
  }
}

// ---------------------------------------------------------------- flash attention v4: 32x32 MFMA + permlane32_swap, in-register P
// 2-wave blocks, single-buffered K/V, 4-barrier counted-vmcnt schedule (r6-verified).
// Q: (B,H,N,HD) bf16 pre-scaled by log2(e)/HD; K: (B,H,N,HD) bf16; Vt: (B,H,HD,N) bf16; O: (B,N,D) bf16
__global__ __launch_bounds__(128) void k_flash(const u16* __restrict__ Q, const u16* __restrict__ Kb,
                                               const u16* __restrict__ Vt, u16* __restrict__ O){
  __shared__ union SM {
    struct { u16 k[64*128]; u16 v[128*64]; } s;   // 16KB + 16KB
    u16 ob[64*128];                               // 16KB epilogue buffer
  } sm;
  const int tid = threadIdx.x, lane = tid & 63, w = tid >> 6;   // w in {0,1}
  const int bid = blockIdx.x;
  const int qt = bid & 31, h = (bid>>5)&15, b = bid>>9;
  const int bh = b*NH + h;
  const int qb0 = qt*64;
  const int hi = lane >> 5, qi = lane & 31;     // 32x32 lane split
  const u16* Kb2 = Kb + (size_t)bh*SEQ*HD;
  const u16* Vt2 = Vt + (size_t)bh*SEQ*HD;

  // Q as 32x32 B-fragment: lane holds col q = qi, k-rows d = ks*16 + hi*8 + j
  bfx8 qf[8];
  {
    const u16* qp = Q + ((size_t)bh*SEQ + qb0 + w*32 + qi)*HD + hi*8;
    #pragma unroll
    for (int ks=0; ks<8; ++ks) qf[ks] = *(const bfx8*)(qp + ks*16);
  }

  // staging offsets (pre-swizzled global source, linear LDS dest); u32 element offsets
  u32 koff[8], voff[8];
  #pragma unroll
  for (int i=0;i<8;i++){
    int off = w*8192 + i*1024 + lane*16;
    int kr = off>>8, kc = off&255;
    int kcs = kc ^ ((kr&15)<<4);                // K: 16-slot swizzle (256B rows)
    koff[i] = kr*HD + (kcs>>1);
    int vr = off>>7, vc = off&127;
    int vcs = vc ^ ((vr&7)<<4);                 // V: 8-slot swizzle (128B rows)
    voff[i] = vr*SEQ + (vcs>>1);
  }

#define STAGE_K(kv_) do { _Pragma("unroll") \
    for (int i_=0;i_<8;i_++) gll16(Kb2 + koff[i_] + (u32)(kv_)*HD, &sm.s.k[w*4096 + i_*512]); } while(0)
#define STAGE_V(kv_) do { _Pragma("unroll") \
    for (int i_=0;i_<8;i_++) gll16(Vt2 + voff[i_] + (u32)(kv_),    &sm.s.v[w*4096 + i_*512]); } while(0)

  fx16 accO0 = {}, accO1 = {}, accO2 = {}, accO3 = {};  // O^T: d = dblk*32 + crow(r,hi), q = qi
  float mrun = -1e30f, lrun = 0.f;

  STAGE_K(0);
  STAGE_V(0);

  for (int t=0; t<32; ++t){
    asm volatile("s_waitcnt vmcnt(8)" ::: "memory");    // K(t) done; V(t) in flight
    __builtin_amdgcn_s_barrier();                       // A: K(t) visible

    // S^T = K @ Q^T : two 32-kk blocks x 32 q, contracted over d=128 (8 slices)
    fx16 stA = {}, stB = {};
    __builtin_amdgcn_s_setprio(1);
    #pragma unroll
    for (int ks=0; ks<8; ++ks){
      const int cb = ks*32 + hi*16;
      int rowA = qi;            // kk block 0
      int rowB = 32 + qi;       // kk block 1
      bfx8 kfa = *(const bfx8*)((const char*)sm.s.k + rowA*256 + (cb ^ ((rowA&15)<<4)));
      bfx8 kfb = *(const bfx8*)((const char*)sm.s.k + rowB*256 + (cb ^ ((rowB&15)<<4)));
      stA = MFMA32_BF16(kfa, qf[ks], stA);
      stB = MFMA32_BF16(kfb, qf[ks], stB);
    }
    __builtin_amdgcn_s_setprio(0);
    __builtin_amdgcn_s_barrier();                       // B: done reading sK
    if (t < 31) STAGE_K(t*64 + 64);                     // K(t+1) lands during softmax+PV

    // online softmax (log2 domain); lane owns q=qi, holds kk: bit2==hi (32 of 64)
    float pm = stA[0];
    #pragma unroll
    for (int i=1;i<16;i++) pm = fmaxf(pm, stA[i]);
    #pragma unroll
    for (int i=0;i<16;i++) pm = fmaxf(pm, stB[i]);
    pm = fmaxf(pm, __shfl_xor(pm, 32, 64));             // full row max (1 shuffle)
    if (!__all(pm <= mrun + 11.0f)){                    // T13 defer-max
      float mn = fmaxf(mrun, pm);
      float al = exp2f(mrun - mn);
      lrun *= al;
      accO0 *= al; accO1 *= al; accO2 *= al; accO3 *= al;
      mrun = mn;
    }
    float ps = 0.f;
    #pragma unroll
    for (int i=0;i<16;i++){
      float p0 = exp2f(stA[i] - mrun); stA[i] = p0; ps += p0;
      float p1 = exp2f(stB[i] - mrun); stB[i] = p1; ps += p1;
    }
    lrun += ps;                                         // lane-local; end-reduce xor32

    // pack P -> bf16 and build PV B-frags via permlane32_swap (T12)
    // slice ks (kk = ks*16 + hi*8 + j): a-quad = regs base..base+3, b-quad = base+4..base+7 of block ks>>1
    bfx8 pv0, pv1, pv2, pv3;
#define PACK(pvx_, stX_, base_) do { \
      unsigned a0 = cvtpk(stX_[base_+0], stX_[base_+1]); \
      unsigned a1 = cvtpk(stX_[base_+2], stX_[base_+3]); \
      unsigned b0 = cvtpk(stX_[base_+4], stX_[base_+5]); \
      unsigned b1 = cvtpk(stX_[base_+6], stX_[base_+7]); \
      asm volatile("v_permlane32_swap_b32 %0, %1" : "+v"(a0), "+v"(b0)); \
      asm volatile("v_permlane32_swap_b32 %0, %1" : "+v"(a1), "+v"(b1)); \
      union { bfx8 v; unsigned u[4]; } pu_; \
      pu_.u[0] = a0; pu_.u[1] = a1; pu_.u[2] = b0; pu_.u[3] = b1; \
      pvx_ = pu_.v; } while(0)
    PACK(pv0, stA, 0);
    PACK(pv1, stA, 8);
    PACK(pv2, stB, 0);
    PACK(pv3, stB, 8);
#undef PACK

    asm volatile("s_waitcnt vmcnt(8)" ::: "memory");    // V(t) done; K(t+1) in flight (t=31: 8 excess ok? no-K staged -> still >=0 outstanding? at t=31 outstanding = V(31)[8] only -> vmcnt(8) no-op; need 0)
    if (t == 31) asm volatile("s_waitcnt vmcnt(0)" ::: "memory");
    __builtin_amdgcn_s_barrier();                       // C: V(t) visible

    // O^T += V^T @ P^T : 4 d-blocks x 4 kk-slices
    __builtin_amdgcn_s_setprio(1);
    #pragma unroll
    for (int dblk=0; dblk<4; ++dblk){
      const int row = dblk*32 + qi;
      const int swz = (row&7)<<4;
      const char* vrow = (const char*)sm.s.v + row*128;
      bfx8 vf0 = *(const bfx8*)(vrow + ((0*32 + hi*16) ^ swz));
      bfx8 vf1 = *(const bfx8*)(vrow + ((1*32 + hi*16) ^ swz));
      bfx8 vf2 = *(const bfx8*)(vrow + ((2*32 + hi*16) ^ swz));
      bfx8 vf3 = *(const bfx8*)(vrow + ((3*32 + hi*16) ^ swz));
      fx16 a = (dblk==0)?accO0:(dblk==1)?accO1:(dblk==2)?accO2:accO3;
      a = MFMA32_BF16(vf0, pv0, a);
      a = MFMA32_BF16(vf1, pv1, a);
      a = MFMA32_BF16(vf2, pv2, a);
      a = MFMA32_BF16(vf3, pv3, a);
      if (dblk==0) accO0 = a; else if (dblk==1) accO1 = a; else if (dblk==2) accO2 = a; else accO3 = a;
    }
    __builtin_amdgcn_s_setprio(0);
    __builtin_amdgcn_s_barrier();                       // D: done reading sV
    if (t < 31) STAGE_V(t*64 + 64);                     // V(t+1) lands during next QK^T+softmax
  }
#undef STAGE_K
#undef STAGE_V

  // epilogue: reduce l, O^T regs -> LDS u16 (swizzled) -> coalesced bf16 global
  {
    float l = lrun + __shfl_xor(lrun, 32, 64);
    float inv = 1.0f / l;
    int q = w*32 + qi;
    char* obr = (char*)sm.ob + q*256;
    const int swz = (q&7)<<4;
#define OWRITE(accX_, dblk_) do { _Pragma("unroll") \
    for (int p=0;p<8;p++){ \
      int d = dblk_*32 + 2*(p&1) + 8*(p>>1) + 4*hi; \
      unsigned wv = cvtpk(accX_[2*p]*inv, accX_[2*p+1]*inv); \
      *(unsigned*)(obr + ((d*2) ^ swz)) = wv; } } while(0)
    OWRITE(accO0, 0); OWRITE(accO1, 1); OWRITE(accO2, 2); OWRITE(accO3, 3);
#undef OWRITE
  }
  __syncthreads();
  {
    int q2 = tid>>1, c0 = (tid&1)*64;
    u16* dst = O + (size_t)(b*SEQ + qb0 + q2)*DM + h*HD + c0;
    #pragma unroll
    for (int jj=0;jj<8;jj++){
      int d0 = c0 + jj*8;
      bfx8 v = *(const bfx8*)((const char*)sm.ob + q2*256 + ((d0*2) ^ ((q2&7)<<4)));
      *(bfx8*)(dst + jj*8) = v;
    }
  }
}

// ----------------------------------------------------------------
extern "C" void kernel_launch(void* const* d_in, const int* in_sizes, int n_in,
                              void* d_out, int out_size, void* d_ws, size_t ws_size,
                              hipStream_t stream){
  (void)in_sizes; (void)n_in; (void)out_size; (void)ws_size;
  const float* x  = (const float*)d_in[0];
  const float* cs = (const float*)d_in[1];
  const float* sn = (const float*)d_in[2];
  const float* Wq = (const float*)d_in[3];
  const float* bq = (const float*)d_in[4];
  const float* Wk = (const float*)d_in[5];
  const float* bk = (const float*)d_in[6];
  const float* Wv = (const float*)d_in[7];
  const float* bv = (const float*)d_in[8];
  const float* Wo = (const float*)d_in[9];
  const float* bo = (const float*)d_in[10];
  float* out = (float*)d_out;

  char* ws = (char*)d_ws;
  const size_t MB = 1048576;
  u16* xb   = (u16*)(ws);              // 16 MB
  u16* wt   = (u16*)(ws + 16*MB);      // 24 MB (6144x2048 bf16; Wo reuses first 8MB)
  u16* qb   = (u16*)(ws + 40*MB);      // 16 MB
  u16* kb   = (u16*)(ws + 56*MB);      // 16 MB
  u16* vt   = (u16*)(ws + 72*MB);      // 16 MB
  u16* ob16 = (u16*)(ws + 88*MB);      // 16 MB; total 104 MB

  k_cast<<<8192,256,0,stream>>>(x, xb, 2097152);
  k_twcat<<<dim3(32,32,3),256,0,stream>>>(Wq, Wk, Wv, wt);
  k_gemm_qkv<<<dim3(48,32),256,0,stream>>>(xb, wt, bq, bk, bv, cs, sn, qb, kb, vt);

  // attention -> ob16 (B,N,D) bf16
  k_flash<<<1024,128,0,stream>>>(qb, kb, vt, ob16);

  // output projection
  k_tw<<<dim3(32,32),256,0,stream>>>(Wo, wt);
  k_gemm<<<dim3(16,32),256,0,stream>>>(ob16, wt, bo, out, MR, DM, DM);
}